// Round 11
// baseline (296.743 us; speedup 1.0000x reference)
//
#include <hip/hip_runtime.h>
#include <math.h>

#define N_TOT   4096
#define N_SRC   2048
#define DIMF    256
#define NCLASS  31
#define LAMBDA  0.01f

// median target ranks among the 2,096,128 strict-lower-triangle values.
#define K_TRI1  1048063LL
#define K_TRI2  1048064LL

// ---- ws layout (bytes) ----
#define WS_ACC    0           // 2 doubles
#define WS_HIST0  64          // 4096 u32
#define WS_HISTA  16448       // 4096 u32
#define WS_HISTB  32832       // 4096 u32
#define WS_STATE  51264       // 64 u32 (st[0..7])
#define WS_TICK   51520       // 4 u32 (solver final ticket)
#define WS_META   52288       // 128 i32: ncls[32], m0c[32], cstart[32], blkoff[32]
#define WS_SCAL   52800       // 16 f32: [0]=sigma, [1]=gamma0, [2]=gamma1
#define ZERO_BYTES 53248
#define WS_PERM   53248       // 4096 i32
#define WS_XN     69632       // 4096 f32
#define WS_DS     1048576     // 2048*2048 f32 (lower triangle used)
#define WS_KBLK   17825792    // big hists (8 MB, dead after scanF) then gK (aliased)
#define WS_BIGA   17825792    // 1M u32 (4 MB): (mid,low) counts for target-A hi bin
#define WS_BIGB   22020096    // 1M u32 (4 MB): same for target-B

#define MAXW 224
#define MAXM 112
#define WPAD 114   // u16 row stride = 57 dwords (odd -> conflict-free rows & cols)

__device__ __forceinline__ float bf2f(unsigned short h) {
  return __uint_as_float(((unsigned)h) << 16);
}

// ---------------- 2-wave reductions (solver runs 128 threads) ----------------
__device__ __forceinline__ double blockReduceSum2(double v, double* red) {
#pragma unroll
  for (int o = 32; o > 0; o >>= 1) v += __shfl_down(v, o, 64);
  int w = threadIdx.x >> 6, lane = threadIdx.x & 63;
  __syncthreads();
  if (lane == 0) red[w] = v;
  __syncthreads();
  return red[0] + red[1];
}

__device__ __forceinline__ void blockReduceSumMax2(double s, double mx, double* red,
                                                   double& os, double& om) {
#pragma unroll
  for (int o = 32; o > 0; o >>= 1) {
    s += __shfl_down(s, o, 64);
    double u = __shfl_down(mx, o, 64);
    mx = fmax(mx, u);
  }
  int w = threadIdx.x >> 6, lane = threadIdx.x & 63;
  __syncthreads();
  if (lane == 0) { red[w] = s; red[4 + w] = mx; }
  __syncthreads();
  os = red[0] + red[1];
  om = fmax(red[4], red[5]);
}

// scan over histogram (256 threads)
__device__ void scan_find(const unsigned* hist, int nbins, long long k, unsigned* shOut) {
  __shared__ long long tsum[256];
  int tid = threadIdx.x;
  int per = nbins / 256;
  long long s = 0;
  for (int q = 0; q < per; q++) s += hist[tid * per + q];
  tsum[tid] = s;
  __syncthreads();
  if (tid == 0) {
    long long run = 0;
    for (int t = 0; t < 256; t++) { long long v = tsum[t]; tsum[t] = run; run += v; }
  }
  __syncthreads();
  long long run = tsum[tid];
  for (int q = 0; q < per; q++) {
    unsigned c = hist[tid * per + q];
    if (k >= run && k < run + (long long)c) { shOut[0] = (unsigned)(tid * per + q); shOut[1] = (unsigned)(k - run); }
    run += c;
  }
  __syncthreads();
}

// ---------------- row norms (coalesced, trivial) ----------------
__global__ __launch_bounds__(256) void xn_kernel(const float* __restrict__ sf,
                                                 const float* __restrict__ tf,
                                                 float* __restrict__ xn) {
  int wid = threadIdx.x >> 6, lane = threadIdx.x & 63;
  int row = blockIdx.x * 4 + wid;
  const float* src = (row < N_SRC) ? (sf + (size_t)row * DIMF) : (tf + (size_t)(row - N_SRC) * DIMF);
  float4 v = ((const float4*)src)[lane];
  float s = v.x * v.x + v.y * v.y + v.z * v.z + v.w * v.w;
#pragma unroll
  for (int o = 32; o > 0; o >>= 1) s += __shfl_down(s, o, 64);
  if (lane == 0) xn[row] = s;
}

// ------- source pairwise sq-dists (triangle), pipelined staging, fused hist0,
// ------- and cooperative zeroing of the big (mid,low) histograms -------
__global__ __launch_bounds__(256) void dist_k(const float* __restrict__ sf,
                                              const float* __restrict__ xn,
                                              float* __restrict__ Ds,
                                              unsigned* __restrict__ h,
                                              uint4* __restrict__ bigz) {
  __shared__ float As[16][68];
  __shared__ float Bs[16][68];
  __shared__ unsigned lh[4096];
  const int tx = threadIdx.x, ty = threadIdx.y;
  const int tid = ty * 16 + tx;
  // zero the 8 MB big-hist region (consumed by hist1 next kernel)
  {
    uint4 z; z.x = 0; z.y = 0; z.z = 0; z.w = 0;
    for (int q = blockIdx.x * 256 + tid; q < 524288; q += 135168) bigz[q] = z;
  }
  for (int q = tid; q < 4096; q += 256) lh[q] = 0;
  // triangle block index -> (by,bx), by >= bx
  int b = blockIdx.x;
  int by = (int)((sqrtf(8.f * (float)b + 1.f) - 1.f) * 0.5f);
  while ((by + 1) * (by + 2) / 2 <= b) ++by;
  while (by * (by + 1) / 2 > b) --by;
  int bx = b - by * (by + 1) / 2;
  const int R = by * 64, C = bx * 64;
  const int si = tid >> 2, sq = tid & 3;
  // software-pipelined staging: prefetch kc+16 into regs during compute of kc
  float4 va = ((const float4*)(sf + (size_t)(R + si) * 256 + 0))[sq];
  float4 vb = ((const float4*)(sf + (size_t)(C + si) * 256 + 0))[sq];
  float acc[4][4] = {};
  for (int kc = 0; kc < 256; kc += 16) {
    As[sq * 4 + 0][si] = va.x; As[sq * 4 + 1][si] = va.y; As[sq * 4 + 2][si] = va.z; As[sq * 4 + 3][si] = va.w;
    Bs[sq * 4 + 0][si] = vb.x; Bs[sq * 4 + 1][si] = vb.y; Bs[sq * 4 + 2][si] = vb.z; Bs[sq * 4 + 3][si] = vb.w;
    __syncthreads();
    if (kc + 16 < 256) {
      va = ((const float4*)(sf + (size_t)(R + si) * 256 + kc + 16))[sq];
      vb = ((const float4*)(sf + (size_t)(C + si) * 256 + kc + 16))[sq];
    }
#pragma unroll
    for (int k = 0; k < 16; k++) {
      float4 a = *(const float4*)&As[k][ty * 4];
      float4 b2 = *(const float4*)&Bs[k][tx * 4];
      acc[0][0] += a.x * b2.x; acc[0][1] += a.x * b2.y; acc[0][2] += a.x * b2.z; acc[0][3] += a.x * b2.w;
      acc[1][0] += a.y * b2.x; acc[1][1] += a.y * b2.y; acc[1][2] += a.y * b2.z; acc[1][3] += a.y * b2.w;
      acc[2][0] += a.z * b2.x; acc[2][1] += a.z * b2.y; acc[2][2] += a.z * b2.z; acc[2][3] += a.z * b2.w;
      acc[3][0] += a.w * b2.x; acc[3][1] += a.w * b2.y; acc[3][2] += a.w * b2.z; acc[3][3] += a.w * b2.w;
    }
    __syncthreads();
  }
  int jbase = C + tx * 4;
  float xnj0 = xn[jbase + 0], xnj1 = xn[jbase + 1], xnj2 = xn[jbase + 2], xnj3 = xn[jbase + 3];
#pragma unroll
  for (int r = 0; r < 4; r++) {
    int i = R + ty * 4 + r;
    float xni = xn[i];
    float v[4];
    v[0] = fmaxf(xni + xnj0 - 2.f * acc[r][0], 0.f);
    v[1] = fmaxf(xni + xnj1 - 2.f * acc[r][1], 0.f);
    v[2] = fmaxf(xni + xnj2 - 2.f * acc[r][2], 0.f);
    v[3] = fmaxf(xni + xnj3 - 2.f * acc[r][3], 0.f);
    if (jbase + 3 < i) {
      float4 o; o.x = v[0]; o.y = v[1]; o.z = v[2]; o.w = v[3];
      ((float4*)&Ds[(size_t)i * 2048 + jbase])[0] = o;
      atomicAdd(&lh[__float_as_uint(v[0]) >> 20], 1u);
      atomicAdd(&lh[__float_as_uint(v[1]) >> 20], 1u);
      atomicAdd(&lh[__float_as_uint(v[2]) >> 20], 1u);
      atomicAdd(&lh[__float_as_uint(v[3]) >> 20], 1u);
    } else {
#pragma unroll
      for (int k = 0; k < 4; k++) {
        if (jbase + k < i) {
          Ds[(size_t)i * 2048 + jbase + k] = v[k];
          atomicAdd(&lh[__float_as_uint(v[k]) >> 20], 1u);
        }
      }
    }
  }
  __syncthreads();
  for (int q = tid; q < 4096; q += 256) if (lh[q]) atomicAdd(&h[q], lh[q]);
}

__global__ __launch_bounds__(256) void scan0_k(const unsigned* __restrict__ h, unsigned* __restrict__ st) {
  __shared__ unsigned r0[2];
  __shared__ unsigned r1[2];
  scan_find(h, 4096, K_TRI1, r0);
  scan_find(h, 4096, K_TRI2, r1);
  if (threadIdx.x == 0) { st[0] = r0[0]; st[1] = r0[1]; st[2] = r1[0]; st[3] = r1[1]; }
}

// ---- radix pass 1 (triangle reads): LDS mid-hist + global (mid,low) big-hist ----
__global__ __launch_bounds__(256) void hist1_k(const float* __restrict__ Ds, const unsigned* __restrict__ st,
                                               unsigned* __restrict__ hA, unsigned* __restrict__ hB,
                                               unsigned* __restrict__ bigA, unsigned* __restrict__ bigB) {
  __shared__ unsigned lA[4096];
  __shared__ unsigned lB[4096];
  for (int i = threadIdx.x; i < 4096; i += 256) { lA[i] = 0; lB[i] = 0; }
  __syncthreads();
  unsigned s0 = st[0], s1 = st[2];
  int gw = (blockIdx.x * 256 + threadIdx.x) >> 6;
  int lane = threadIdx.x & 63;
  const float* row = Ds + (size_t)gw * 2048;
  for (int j = lane; j < gw; j += 64) {
    unsigned u = __float_as_uint(row[j]);
    unsigned hi = u >> 20, mid = (u >> 8) & 0xFFFu;
    if (hi == s0) { atomicAdd(&lA[mid], 1u); atomicAdd(&bigA[u & 0xFFFFFu], 1u); }
    if (hi == s1) { atomicAdd(&lB[mid], 1u); atomicAdd(&bigB[u & 0xFFFFFu], 1u); }
  }
  __syncthreads();
  for (int i = threadIdx.x; i < 4096; i += 256) {
    if (lA[i]) atomicAdd(&hA[i], lA[i]);
    if (lB[i]) atomicAdd(&hB[i], lB[i]);
  }
}

// ------- final scan: mid bin -> low byte from big-hist -> sigma; + bucketing -------
__global__ __launch_bounds__(256) void scanF_k(const unsigned* __restrict__ hA, const unsigned* __restrict__ hB,
                                               const unsigned* __restrict__ bigA, const unsigned* __restrict__ bigB,
                                               const unsigned* __restrict__ st, float* __restrict__ scal,
                                               const int* __restrict__ y, const int* __restrict__ l,
                                               int* __restrict__ perm, int* __restrict__ meta) {
  int tid = threadIdx.x;
  __shared__ unsigned m0[2], m1[2], l0[2], l1[2];
  scan_find(hA, 4096, (long long)st[1], m0);
  scan_find(hB, 4096, (long long)st[3], m1);
  scan_find(bigA + (size_t)m0[0] * 256, 256, (long long)m0[1], l0);
  scan_find(bigB + (size_t)m1[0] * 256, 256, (long long)m1[1], l1);
  if (tid == 0) {
    unsigned v1 = (st[0] << 20) | (m0[0] << 8) | l0[0];
    unsigned v2 = (st[2] << 20) | (m1[0] << 8) | l1[0];
    scal[0] = 0.5f * (__uint_as_float(v1) + __uint_as_float(v2));  // sigma
  }
  // ---- class/domain bucketing ----
  __shared__ unsigned cl[64];
  __shared__ unsigned bs2[64];
  __shared__ unsigned cur[64];
  if (tid < 64) cl[tid] = 0;
  __syncthreads();
  for (int i = tid; i < N_TOT; i += 256) atomicAdd(&cl[y[i] * 2 + l[i]], 1u);
  __syncthreads();
  if (tid == 0) {
    unsigned run = 0;
    for (int b2 = 0; b2 < 62; b2++) { bs2[b2] = run; run += cl[b2]; }
    unsigned run2 = 0, cnt0 = 0;
    for (int c = 0; c < NCLASS; c++) {
      int n = (int)(cl[2 * c] + cl[2 * c + 1]);
      meta[c] = n; meta[32 + c] = (int)cl[2 * c]; meta[64 + c] = (int)bs2[2 * c];
      meta[96 + c] = (int)run2; run2 += (unsigned)(n * n);
      cnt0 += cl[2 * c];
    }
    scal[1] = (float)((double)cnt0 / (4096.0 * 4096.0));
    scal[2] = (float)((double)(N_TOT - cnt0) / (4096.0 * 4096.0));
  }
  __syncthreads();
  if (tid < 64) cur[tid] = bs2[tid];
  __syncthreads();
  for (int i = tid; i < N_TOT; i += 256) {
    int b2 = y[i] * 2 + l[i];
    unsigned pos = atomicAdd(&cur[b2], 1u);
    perm[pos] = i;
  }
}

// ------- build per-class K blocks: lower-triangle tiles + mirrored store -------
__global__ __launch_bounds__(256) void build_k(const float* __restrict__ sf, const float* __restrict__ tf,
                                               const float* __restrict__ xn, const int* __restrict__ perm,
                                               const int* __restrict__ meta, const float* __restrict__ scal,
                                               float* __restrict__ gK) {
  const int c = blockIdx.z;
  const int n = meta[c];
  const int cs = meta[64 + c];
  const int bo = meta[96 + c];
  const int T = (n + 15) >> 4;
  int b = blockIdx.x;
  if (b >= T * (T + 1) / 2) return;
  int by = (int)((sqrtf(8.f * (float)b + 1.f) - 1.f) * 0.5f);
  while ((by + 1) * (by + 2) / 2 <= b) ++by;
  while (by * (by + 1) / 2 > b) --by;
  int bx = b - by * (by + 1) / 2;
  const int i0 = by * 16, j0 = bx * 16;
  const int tx = threadIdx.x, ty = threadIdx.y;
  __shared__ float As[16][260];
  __shared__ float Bs[16][260];
  __shared__ float ot[16][17];
  __shared__ int ra[16];
  __shared__ int rb[16];
  int tid = ty * 16 + tx;
  if (tid < 16) { int il = i0 + tid; ra[tid] = (il < n) ? perm[cs + il] : -1; }
  else if (tid < 32) { int jl = j0 + tid - 16; rb[tid - 16] = (jl < n) ? perm[cs + jl] : -1; }
  __syncthreads();
  for (int e = tid; e < 1024; e += 256) {
    int r = e >> 6, q = e & 63;
    int g = ra[r];
    if (g >= 0) {
      const float* src = (g < N_SRC) ? (sf + (size_t)g * DIMF) : (tf + (size_t)(g - N_SRC) * DIMF);
      ((float4*)&As[r][q * 4])[0] = ((const float4*)src)[q];
    }
    int g2 = rb[r];
    if (g2 >= 0) {
      const float* src = (g2 < N_SRC) ? (sf + (size_t)g2 * DIMF) : (tf + (size_t)(g2 - N_SRC) * DIMF);
      ((float4*)&Bs[r][q * 4])[0] = ((const float4*)src)[q];
    }
  }
  __syncthreads();
  int il = i0 + ty, jl = j0 + tx;
  float val = 0.f;
  if (il < n && jl < n) {
    float dot = 0.f;
    const float4* a4 = (const float4*)&As[ty][0];
    const float4* b4 = (const float4*)&Bs[tx][0];
#pragma unroll 16
    for (int q = 0; q < 64; q++) {
      float4 a = a4[q], b2 = b4[q];
      dot += a.x * b2.x + a.y * b2.y + a.z * b2.z + a.w * b2.w;
    }
    int gi = ra[ty], gj = rb[tx];
    float d = xn[gi] + xn[gj] - 2.f * dot;
    val = expf(-d / scal[0]);
    gK[(size_t)bo + (size_t)il * n + jl] = val;
  }
  ot[ty][tx] = val;
  __syncthreads();
  if (by != bx) {
    int il2 = j0 + ty, jl2 = i0 + tx;
    if (il2 < n && jl2 < n) gK[(size_t)bo + (size_t)il2 * n + jl2] = ot[tx][ty];
  }
}

// ---------------- per-(class,domain) Newton-PCG + fused final (128 threads) ----------------
// 2-wave block: same math as R10 (it=0 shortcut, frozen Jacobi, inexact CG),
// but half-width barriers on the ~300-barrier critical path.
__global__ __launch_bounds__(128) void solver_k(const float* __restrict__ gK, const int* __restrict__ meta,
                                                const float* __restrict__ scal, double* __restrict__ acc,
                                                unsigned* __restrict__ tick, float* __restrict__ out) {
  const int c = blockIdx.x >> 1, d = blockIdx.x & 1;
  const int n = meta[c];
  const int m0 = meta[32 + c];
  const int m = d ? (n - m0) : m0;
  const int c0 = d ? m0 : 0;
  const int bo = meta[96 + c];
  const float gamma = scal[1 + d];
  const int tid = threadIdx.x;
  const int wv = tid >> 6, lane = tid & 63;

  __shared__ unsigned short Wl[MAXW * WPAD];   // 51072 B
  __shared__ float pS[2 * MAXM];
  __shared__ float pD[2 * MAXM];
  __shared__ float Av[MAXW];
  __shared__ float Sv[MAXW];
  __shared__ float Uv[MAXW];
  __shared__ float Bq[MAXW];
  __shared__ float bc[MAXM];
  __shared__ float th[MAXM + 1];
  __shared__ float gv[MAXM];
  __shared__ float dgv[MAXM];
  __shared__ float pv[MAXM + 1];
  __shared__ float rv[MAXM + 1];
  __shared__ float zv[MAXM + 1];
  __shared__ float xv[MAXM + 1];
  __shared__ double red[8];

  const float* K = gK + bo;
  const int st2 = n;
  const int mp2 = (m + 1) & ~1;
  const int iw0 = (n * wv) >> 1, iw1 = (n * (wv + 1)) >> 1;   // per-wave n-chunk

  for (int i = tid >> 2; i < n; i += 32) {
    const float* Kr = K + (size_t)i * st2 + c0;
    unsigned short* Wr = Wl + i * WPAD;
    for (int j = (tid & 3); j < m; j += 4) {
      unsigned u = __float_as_uint(Kr[j]);
      u += 0x7fffu + ((u >> 16) & 1u);   // RNE to bf16
      Wr[j] = (unsigned short)(u >> 16);
    }
    if ((tid & 3) == 0 && (m & 1)) Wr[m] = 0;
  }
  {
    const int r0 = (m * wv) >> 1, r1 = (m * (wv + 1)) >> 1;
    for (int j = lane; j < m; j += 64) {
      const float* Kr = K + (size_t)(c0 + j) * st2 + c0;
      float s = 0.f;
      for (int r = r0; r < r1; r++) s += Kr[r];
      pS[wv * MAXM + j] = s;
    }
  }
  __syncthreads();
  for (int j = tid; j < mp2; j += 128) {
    if (j < m) bc[j] = (pS[j] + pS[MAXM + j]) * (1.0f / 4096.0f);
    th[j] = 0.f;
  }
  __syncthreads();

  for (int it = 0; it < 25; it++) {
    double o = 0.0;
    if (it == 0) {
      const float s0c = gamma * expf(-1.f);
      for (int i = tid; i < n; i += 128) { Av[i] = 0.f; Sv[i] = s0c; o += (double)s0c; }
    } else {
      for (int i = tid; i < n; i += 128) {
        const unsigned short* Wr = Wl + i * WPAD;
        float a = 0.f;
#pragma unroll 4
        for (int j = 0; j < mp2; j += 2) {
          unsigned u = *(const unsigned*)(Wr + j);
          a += __uint_as_float(u << 16) * th[j]
             + __uint_as_float(u & 0xffff0000u) * th[j + 1];
        }
        Av[i] = a;
      }
      __syncthreads();
      for (int i = tid; i < n; i += 128) {
        float si = gamma * expf(fminf(Av[i] - 1.f, 30.f));
        Sv[i] = si; o += (double)si;
      }
      for (int j = tid; j < m; j += 128) {
        float t_ = th[j];
        o += (double)(-bc[j] * t_ + LAMBDA * t_ * t_);
      }
    }
    __syncthreads();
    // ---- gradient (+ Jacobi diag at it==0 only; frozen after) ----
    if (it == 0) {
      for (int j = lane; j < m; j += 64) {
        const unsigned short* Wc = Wl + j;
        float s_ = 0.f, ds_ = 0.f;
        int i = iw0;
        for (; i + 3 < iw1; i += 4) {
          float w0 = bf2f(Wc[(i + 0) * WPAD]), w1 = bf2f(Wc[(i + 1) * WPAD]);
          float w2 = bf2f(Wc[(i + 2) * WPAD]), w3 = bf2f(Wc[(i + 3) * WPAD]);
          float a0 = w0 * Sv[i], a1 = w1 * Sv[i + 1], a2 = w2 * Sv[i + 2], a3 = w3 * Sv[i + 3];
          s_ += a0 + a1 + a2 + a3;
          ds_ += a0 * w0 + a1 * w1 + a2 * w2 + a3 * w3;
        }
        for (; i < iw1; i++) { float w = bf2f(Wc[i * WPAD]); float a = w * Sv[i]; s_ += a; ds_ += a * w; }
        pS[wv * MAXM + j] = s_; pD[wv * MAXM + j] = ds_;
      }
    } else {
      for (int j = lane; j < m; j += 64) {
        const unsigned short* Wc = Wl + j;
        float s_ = 0.f;
        int i = iw0;
        for (; i + 3 < iw1; i += 4)
          s_ += bf2f(Wc[(i+0)*WPAD]) * Sv[i]   + bf2f(Wc[(i+1)*WPAD]) * Sv[i+1]
              + bf2f(Wc[(i+2)*WPAD]) * Sv[i+2] + bf2f(Wc[(i+3)*WPAD]) * Sv[i+3];
        for (; i < iw1; i++) s_ += bf2f(Wc[i * WPAD]) * Sv[i];
        pS[wv * MAXM + j] = s_;
      }
    }
    __syncthreads();
    double gm = 0.0;
    for (int j = tid; j < m; j += 128) {
      float s_ = pS[j] + pS[MAXM + j];
      if (it == 0) dgv[j] = pD[j] + pD[MAXM + j] + 2.f * LAMBDA;
      float g = s_ - bc[j] + 2.f * LAMBDA * th[j];
      gv[j] = g;
      double ag = fabs((double)g); if (ag > gm) gm = ag;
    }
    double obj, gmax;
    blockReduceSumMax2(o, gm, red, obj, gmax);
    if (gmax < 1e-5) break;

    // ---- PCG solve H x = -g (frozen Jacobi precond), inexact-Newton tol ----
    const double tolf = (it == 0) ? 1e-2 : ((it == 1) ? 1e-3 : 1e-4);
    double rz = 0.0;
    for (int j = tid; j < mp2; j += 128) {
      float r0 = (j < m) ? -gv[j] : 0.f;
      float z0 = (j < m) ? r0 / dgv[j] : 0.f;
      rv[j] = r0; zv[j] = z0; pv[j] = z0; xv[j] = 0.f;
      rz += (double)r0 * (double)z0;
    }
    rz = blockReduceSum2(rz, red);
    double rz0 = rz;
    for (int cg = 0; cg < 12; cg++) {
      __syncthreads();
      for (int i = tid; i < n; i += 128) {
        const unsigned short* Wr = Wl + i * WPAD;
        float a = 0.f;
#pragma unroll 4
        for (int j = 0; j < mp2; j += 2) {
          unsigned u = *(const unsigned*)(Wr + j);
          a += __uint_as_float(u << 16) * pv[j]
             + __uint_as_float(u & 0xffff0000u) * pv[j + 1];
        }
        Uv[i] = a * Sv[i];
      }
      __syncthreads();
      for (int j = lane; j < m; j += 64) {
        const unsigned short* Wc = Wl + j;
        float q = 0.f;
        int i = iw0;
        for (; i + 3 < iw1; i += 4)
          q += bf2f(Wc[(i+0)*WPAD]) * Uv[i]   + bf2f(Wc[(i+1)*WPAD]) * Uv[i+1]
             + bf2f(Wc[(i+2)*WPAD]) * Uv[i+2] + bf2f(Wc[(i+3)*WPAD]) * Uv[i+3];
        for (; i < iw1; i++) q += bf2f(Wc[i * WPAD]) * Uv[i];
        pS[wv * MAXM + j] = q;
      }
      __syncthreads();
      double pq = 0.0;
      for (int j = tid; j < m; j += 128) {
        float q = pS[j] + pS[MAXM + j] + 2.f * LAMBDA * pv[j];
        Bq[j] = q;
        pq += (double)pv[j] * (double)q;
      }
      pq = blockReduceSum2(pq, red);
      if (!(pq > 0.0)) break;
      float alpha = (float)(rz / pq);
      double rznew = 0.0;
      for (int j = tid; j < m; j += 128) {
        xv[j] += alpha * pv[j];
        float rn = rv[j] - alpha * Bq[j];
        rv[j] = rn;
        float zn = rn / dgv[j];
        zv[j] = zn;
        rznew += (double)rn * (double)zn;
      }
      rznew = blockReduceSum2(rznew, red);
      if (rznew < tolf * rz0 || cg == 11) break;
      float beta = (float)(rznew / rz);
      for (int j = tid; j < m; j += 128) pv[j] = zv[j] + beta * pv[j];
      rz = rznew;
    }
    __syncthreads();
    double gtpl = 0.0, pml = 0.0;
    for (int j = tid; j < m; j += 128) {
      gtpl += (double)gv[j] * (double)xv[j];
      double ax = fabs((double)xv[j]); if (ax > pml) pml = ax;
    }
    double gtp, pmax;
    blockReduceSumMax2(gtpl, pml, red, gtp, pmax);
    if (!(gtp < 0.0)) break;

    float t = 1.f;
    if (-gtp >= 1e-4) {
      for (int i = tid; i < n; i += 128) {
        const unsigned short* Wr = Wl + i * WPAD;
        float a = 0.f;
#pragma unroll 4
        for (int j = 0; j < mp2; j += 2) {
          unsigned u = *(const unsigned*)(Wr + j);
          a += __uint_as_float(u << 16) * xv[j]
             + __uint_as_float(u & 0xffff0000u) * xv[j + 1];
        }
        Bq[i] = a;
      }
      __syncthreads();
      for (int ls = 0; ls < 10; ls++) {
        double ol = 0.0;
        for (int i = tid; i < n; i += 128)
          ol += (double)(gamma * expf(fminf(Av[i] + t * Bq[i] - 1.f, 30.f)));
        for (int j = tid; j < m; j += 128) {
          float tj = th[j] + t * xv[j];
          ol += (double)(-bc[j] * tj + LAMBDA * tj * tj);
        }
        double ot2 = blockReduceSum2(ol, red);
        if (ot2 <= obj + 1e-4 * (double)t * gtp) break;
        t *= 0.5f;
      }
    }
    for (int j = tid; j < mp2; j += 128) th[j] += t * xv[j];
    __syncthreads();
    if ((double)t * pmax < 1e-7) break;
  }

  // ---- final exact f32 evaluation (global K, f32 theta) ----
  __syncthreads();
  for (int i = tid; i < n; i += 128) {
    const float* Kr = K + (size_t)i * st2 + c0;
    float a = 0.f;
    int j = 0;
    for (; j + 7 < m; j += 8)
      a += th[j] * Kr[j] + th[j+1] * Kr[j+1] + th[j+2] * Kr[j+2] + th[j+3] * Kr[j+3]
         + th[j+4] * Kr[j+4] + th[j+5] * Kr[j+5] + th[j+6] * Kr[j+6] + th[j+7] * Kr[j+7];
    for (; j < m; j++) a += th[j] * Kr[j];
    Av[i] = a;
  }
  __syncthreads();
  double t1l = 0.0, t2l = 0.0;
  for (int i = tid; i < n; i += 128) t2l += (double)(gamma * expf(fminf(Av[i] - 1.f, 30.f)));
  for (int j = tid; j < m; j += 128) t1l += (double)(bc[j] * th[j]);
  double t1 = blockReduceSum2(t1l, red);
  double t2 = blockReduceSum2(t2l, red);
  if (tid == 0) {
    atomicAdd(&acc[0], t1);
    atomicAdd(&acc[1], t2);
    __threadfence();
    unsigned old = __hip_atomic_fetch_add(&tick[0], 1u, __ATOMIC_ACQ_REL, __HIP_MEMORY_SCOPE_AGENT);
    if (old == 61u) {
      double a0 = __hip_atomic_load(&acc[0], __ATOMIC_RELAXED, __HIP_MEMORY_SCOPE_AGENT);
      double a1 = __hip_atomic_load(&acc[1], __ATOMIC_RELAXED, __HIP_MEMORY_SCOPE_AGENT);
      out[0] = (float)(a0 - a1);
    }
  }
}

// ---------------- launcher ----------------
extern "C" void kernel_launch(void* const* d_in, const int* in_sizes, int n_in,
                              void* d_out, int out_size, void* d_ws, size_t ws_size,
                              hipStream_t stream) {
  const float* sf = (const float*)d_in[0];
  const float* tf = (const float*)d_in[1];
  const int* y = (const int*)d_in[2];
  const int* l = (const int*)d_in[3];
  char* ws = (char*)d_ws;

  double*   acc    = (double*)(ws + WS_ACC);
  unsigned* hist0  = (unsigned*)(ws + WS_HIST0);
  unsigned* histA  = (unsigned*)(ws + WS_HISTA);
  unsigned* histB  = (unsigned*)(ws + WS_HISTB);
  unsigned* state  = (unsigned*)(ws + WS_STATE);
  unsigned* tick   = (unsigned*)(ws + WS_TICK);
  int*      meta   = (int*)(ws + WS_META);
  float*    scal   = (float*)(ws + WS_SCAL);
  int*      perm   = (int*)(ws + WS_PERM);
  float*    xnp    = (float*)(ws + WS_XN);
  float*    Ds     = (float*)(ws + WS_DS);
  unsigned* bigA   = (unsigned*)(ws + WS_BIGA);
  unsigned* bigB   = (unsigned*)(ws + WS_BIGB);
  float*    gK     = (float*)(ws + WS_KBLK);   // aliases big region (dead after scanF)

  hipMemsetAsync(d_ws, 0, ZERO_BYTES, stream);
  hipLaunchKernelGGL(xn_kernel, dim3(1024), dim3(256), 0, stream, sf, tf, xnp);
  hipLaunchKernelGGL(dist_k, dim3(528), dim3(16, 16), 0, stream, sf, xnp, Ds, hist0, (uint4*)bigA);
  hipLaunchKernelGGL(scan0_k, dim3(1), dim3(256), 0, stream, hist0, state);
  hipLaunchKernelGGL(hist1_k, dim3(512), dim3(256), 0, stream, Ds, state, histA, histB, bigA, bigB);
  hipLaunchKernelGGL(scanF_k, dim3(1), dim3(256), 0, stream, histA, histB, bigA, bigB, state, scal, y, l, perm, meta);
  hipLaunchKernelGGL(build_k, dim3(105, 1, NCLASS), dim3(16, 16), 0, stream, sf, tf, xnp, perm, meta, scal, gK);
  hipLaunchKernelGGL(solver_k, dim3(62), dim3(128), 0, stream, gK, meta, scal, acc, tick, (float*)d_out);
}

// Round 12
// 238.372 us; speedup vs baseline: 1.2449x; 1.2449x over previous
//
#include <hip/hip_runtime.h>
#include <math.h>

#define N_TOT   4096
#define N_SRC   2048
#define DIMF    256
#define NCLASS  31
#define LAMBDA  0.01f

// median target ranks among the 2,096,128 strict-lower-triangle values.
#define K_TRI1  1048063LL
#define K_TRI2  1048064LL

// ---- ws layout (bytes) ----
#define WS_ACC    0           // 2 doubles
#define WS_HIST0  64          // 4096 u32
#define WS_HISTA  16448       // 4096 u32
#define WS_HISTB  32832       // 4096 u32
#define WS_H2A    49216       // 256 u32
#define WS_H2B    50240       // 256 u32
#define WS_STATE  51264       // 64 u32 (st[0..7])
#define WS_TICK   51520       // 4 u32 (solver final ticket)
#define WS_META   52288       // 128 i32: ncls[32], m0c[32], cstart[32], blkoff[32]
#define WS_SCAL   52800       // 16 f32: [0]=sigma, [1]=gamma0, [2]=gamma1
#define ZERO_BYTES 53248
#define WS_PERM   53248       // 4096 i32
#define WS_XN     69632       // 4096 f32
#define WS_DS     1048576     // 2048*2048 f32 (lower triangle used)
#define WS_KBLK   17825792    // class K blocks (8 MB budget)

#define MAXW 224
#define MAXM 112
#define WPAD 114   // u16 row stride = 57 dwords (odd -> conflict-free rows & cols)

__device__ __forceinline__ float bf2f(unsigned short h) {
  return __uint_as_float(((unsigned)h) << 16);
}

// ---------------- reductions (256 threads) ----------------
__device__ __forceinline__ double blockReduceSum(double v, double* red) {
#pragma unroll
  for (int o = 32; o > 0; o >>= 1) v += __shfl_down(v, o, 64);
  int w = threadIdx.x >> 6, lane = threadIdx.x & 63;
  __syncthreads();
  if (lane == 0) red[w] = v;
  __syncthreads();
  return red[0] + red[1] + red[2] + red[3];
}

__device__ __forceinline__ void blockReduceSumMax(double s, double mx, double* red,
                                                  double& os, double& om) {
#pragma unroll
  for (int o = 32; o > 0; o >>= 1) {
    s += __shfl_down(s, o, 64);
    double u = __shfl_down(mx, o, 64);
    mx = fmax(mx, u);
  }
  int w = threadIdx.x >> 6, lane = threadIdx.x & 63;
  __syncthreads();
  if (lane == 0) { red[w] = s; red[4 + w] = mx; }
  __syncthreads();
  os = red[0] + red[1] + red[2] + red[3];
  om = fmax(fmax(red[4], red[5]), fmax(red[6], red[7]));
}

// scan over histogram (256 threads)
__device__ void scan_find(const unsigned* hist, int nbins, long long k, unsigned* shOut) {
  __shared__ long long tsum[256];
  int tid = threadIdx.x;
  int per = nbins / 256;
  long long s = 0;
  for (int q = 0; q < per; q++) s += hist[tid * per + q];
  tsum[tid] = s;
  __syncthreads();
  if (tid == 0) {
    long long run = 0;
    for (int t = 0; t < 256; t++) { long long v = tsum[t]; tsum[t] = run; run += v; }
  }
  __syncthreads();
  long long run = tsum[tid];
  for (int q = 0; q < per; q++) {
    unsigned c = hist[tid * per + q];
    if (k >= run && k < run + (long long)c) { shOut[0] = (unsigned)(tid * per + q); shOut[1] = (unsigned)(k - run); }
    run += c;
  }
  __syncthreads();
}

// ---------------- row norms (coalesced, trivial) ----------------
__global__ __launch_bounds__(256) void xn_kernel(const float* __restrict__ sf,
                                                 const float* __restrict__ tf,
                                                 float* __restrict__ xn) {
  int wid = threadIdx.x >> 6, lane = threadIdx.x & 63;
  int row = blockIdx.x * 4 + wid;
  const float* src = (row < N_SRC) ? (sf + (size_t)row * DIMF) : (tf + (size_t)(row - N_SRC) * DIMF);
  float4 v = ((const float4*)src)[lane];
  float s = v.x * v.x + v.y * v.y + v.z * v.z + v.w * v.w;
#pragma unroll
  for (int o = 32; o > 0; o >>= 1) s += __shfl_down(s, o, 64);
  if (lane == 0) xn[row] = s;
}

// ------- source pairwise sq-dists (triangle), KC=64 tiles (8 barriers), fused hist0 -------
__global__ __launch_bounds__(256) void dist_k(const float* __restrict__ sf,
                                              const float* __restrict__ xn,
                                              float* __restrict__ Ds,
                                              unsigned* __restrict__ h) {
  __shared__ float As[64][68];
  __shared__ float Bs[64][68];
  __shared__ unsigned lh[4096];
  const int tx = threadIdx.x, ty = threadIdx.y;
  const int tid = ty * 16 + tx;
  for (int q = tid; q < 4096; q += 256) lh[q] = 0;
  // triangle block index -> (by,bx), by >= bx
  int b = blockIdx.x;
  int by = (int)((sqrtf(8.f * (float)b + 1.f) - 1.f) * 0.5f);
  while ((by + 1) * (by + 2) / 2 <= b) ++by;
  while (by * (by + 1) / 2 > b) --by;
  int bx = b - by * (by + 1) / 2;
  const int R = by * 64, C = bx * 64;
  const int si = tid >> 2, sq = tid & 3;
  // prefetch tile 0 (16 float4s per matrix across the block; 4 per thread)
  float4 va[4], vb[4];
#pragma unroll
  for (int qq = 0; qq < 4; qq++) {
    va[qq] = ((const float4*)(sf + (size_t)(R + si) * 256))[sq + qq * 4];
    vb[qq] = ((const float4*)(sf + (size_t)(C + si) * 256))[sq + qq * 4];
  }
  float acc[4][4] = {};
  for (int kc = 0; kc < 256; kc += 64) {
#pragma unroll
    for (int qq = 0; qq < 4; qq++) {
      int kb = (sq + qq * 4) * 4;
      As[kb + 0][si] = va[qq].x; As[kb + 1][si] = va[qq].y; As[kb + 2][si] = va[qq].z; As[kb + 3][si] = va[qq].w;
      Bs[kb + 0][si] = vb[qq].x; Bs[kb + 1][si] = vb[qq].y; Bs[kb + 2][si] = vb[qq].z; Bs[kb + 3][si] = vb[qq].w;
    }
    __syncthreads();
    if (kc + 64 < 256) {
#pragma unroll
      for (int qq = 0; qq < 4; qq++) {
        va[qq] = ((const float4*)(sf + (size_t)(R + si) * 256 + kc + 64))[sq + qq * 4];
        vb[qq] = ((const float4*)(sf + (size_t)(C + si) * 256 + kc + 64))[sq + qq * 4];
      }
    }
#pragma unroll 16
    for (int k = 0; k < 64; k++) {
      float4 a = *(const float4*)&As[k][ty * 4];
      float4 b2 = *(const float4*)&Bs[k][tx * 4];
      acc[0][0] += a.x * b2.x; acc[0][1] += a.x * b2.y; acc[0][2] += a.x * b2.z; acc[0][3] += a.x * b2.w;
      acc[1][0] += a.y * b2.x; acc[1][1] += a.y * b2.y; acc[1][2] += a.y * b2.z; acc[1][3] += a.y * b2.w;
      acc[2][0] += a.z * b2.x; acc[2][1] += a.z * b2.y; acc[2][2] += a.z * b2.z; acc[2][3] += a.z * b2.w;
      acc[3][0] += a.w * b2.x; acc[3][1] += a.w * b2.y; acc[3][2] += a.w * b2.z; acc[3][3] += a.w * b2.w;
    }
    __syncthreads();
  }
  int jbase = C + tx * 4;
  float xnj0 = xn[jbase + 0], xnj1 = xn[jbase + 1], xnj2 = xn[jbase + 2], xnj3 = xn[jbase + 3];
#pragma unroll
  for (int r = 0; r < 4; r++) {
    int i = R + ty * 4 + r;
    float xni = xn[i];
    float v[4];
    v[0] = fmaxf(xni + xnj0 - 2.f * acc[r][0], 0.f);
    v[1] = fmaxf(xni + xnj1 - 2.f * acc[r][1], 0.f);
    v[2] = fmaxf(xni + xnj2 - 2.f * acc[r][2], 0.f);
    v[3] = fmaxf(xni + xnj3 - 2.f * acc[r][3], 0.f);
    if (jbase + 3 < i) {
      float4 o; o.x = v[0]; o.y = v[1]; o.z = v[2]; o.w = v[3];
      ((float4*)&Ds[(size_t)i * 2048 + jbase])[0] = o;
      atomicAdd(&lh[__float_as_uint(v[0]) >> 20], 1u);
      atomicAdd(&lh[__float_as_uint(v[1]) >> 20], 1u);
      atomicAdd(&lh[__float_as_uint(v[2]) >> 20], 1u);
      atomicAdd(&lh[__float_as_uint(v[3]) >> 20], 1u);
    } else {
#pragma unroll
      for (int k = 0; k < 4; k++) {
        if (jbase + k < i) {
          Ds[(size_t)i * 2048 + jbase + k] = v[k];
          atomicAdd(&lh[__float_as_uint(v[k]) >> 20], 1u);
        }
      }
    }
  }
  __syncthreads();
  for (int q = tid; q < 4096; q += 256) if (lh[q]) atomicAdd(&h[q], lh[q]);
}

__global__ __launch_bounds__(256) void scan0_k(const unsigned* __restrict__ h, unsigned* __restrict__ st) {
  __shared__ unsigned r0[2];
  __shared__ unsigned r1[2];
  scan_find(h, 4096, K_TRI1, r0);
  scan_find(h, 4096, K_TRI2, r1);
  if (threadIdx.x == 0) { st[0] = r0[0]; st[1] = r0[1]; st[2] = r1[0]; st[3] = r1[1]; }
}

// ---------------- radix pass 1 (triangle reads) ----------------
__global__ __launch_bounds__(256) void hist1_k(const float* __restrict__ Ds, const unsigned* __restrict__ st,
                                               unsigned* __restrict__ hA, unsigned* __restrict__ hB) {
  __shared__ unsigned lA[4096];
  __shared__ unsigned lB[4096];
  for (int i = threadIdx.x; i < 4096; i += 256) { lA[i] = 0; lB[i] = 0; }
  __syncthreads();
  unsigned s0 = st[0], s1 = st[2];
  int gw = (blockIdx.x * 256 + threadIdx.x) >> 6;
  int lane = threadIdx.x & 63;
  const float* row = Ds + (size_t)gw * 2048;
  for (int j = lane; j < gw; j += 64) {
    unsigned u = __float_as_uint(row[j]);
    unsigned hi = u >> 20, mid = (u >> 8) & 0xFFFu;
    if (hi == s0) atomicAdd(&lA[mid], 1u);
    if (hi == s1) atomicAdd(&lB[mid], 1u);
  }
  __syncthreads();
  for (int i = threadIdx.x; i < 4096; i += 256) {
    if (lA[i]) atomicAdd(&hA[i], lA[i]);
    if (lB[i]) atomicAdd(&hB[i], lB[i]);
  }
}

__global__ __launch_bounds__(256) void scan1_k(const unsigned* __restrict__ hA, const unsigned* __restrict__ hB,
                                               unsigned* __restrict__ st) {
  __shared__ unsigned r0[2];
  __shared__ unsigned r1[2];
  long long kA = (long long)st[1];
  long long kB = (long long)st[3];
  scan_find(hA, 4096, kA, r0);
  scan_find(hB, 4096, kB, r1);
  if (threadIdx.x == 0) { st[4] = r0[0]; st[5] = r0[1]; st[6] = r1[0]; st[7] = r1[1]; }
}

// ---------------- radix pass 2 (triangle reads) ----------------
__global__ __launch_bounds__(256) void hist2_k(const float* __restrict__ Ds, const unsigned* __restrict__ st,
                                               unsigned* __restrict__ hA, unsigned* __restrict__ hB) {
  __shared__ unsigned lA[256];
  __shared__ unsigned lB[256];
  lA[threadIdx.x] = 0; lB[threadIdx.x] = 0;
  __syncthreads();
  unsigned p0 = (st[0] << 12) | st[4];
  unsigned p1 = (st[2] << 12) | st[6];
  int gw = (blockIdx.x * 256 + threadIdx.x) >> 6;
  int lane = threadIdx.x & 63;
  const float* row = Ds + (size_t)gw * 2048;
  for (int j = lane; j < gw; j += 64) {
    unsigned u = __float_as_uint(row[j]);
    unsigned pre = u >> 8;
    if (pre == p0) atomicAdd(&lA[u & 0xFFu], 1u);
    if (pre == p1) atomicAdd(&lB[u & 0xFFu], 1u);
  }
  __syncthreads();
  if (lA[threadIdx.x]) atomicAdd(&hA[threadIdx.x], lA[threadIdx.x]);
  if (lB[threadIdx.x]) atomicAdd(&hB[threadIdx.x], lB[threadIdx.x]);
}

// ------- scan2 (sigma) + class/domain bucketing, single block -------
__global__ __launch_bounds__(256) void scan2b_k(const unsigned* __restrict__ hA, const unsigned* __restrict__ hB,
                                                const unsigned* __restrict__ st, float* __restrict__ scal,
                                                const int* __restrict__ y, const int* __restrict__ l,
                                                int* __restrict__ perm, int* __restrict__ meta) {
  int tid = threadIdx.x;
  __shared__ unsigned r0[2];
  __shared__ unsigned r1[2];
  scan_find(hA, 256, (long long)st[5], r0);
  scan_find(hB, 256, (long long)st[7], r1);
  if (tid == 0) {
    unsigned v1 = (st[0] << 20) | (st[4] << 8) | r0[0];
    unsigned v2 = (st[2] << 20) | (st[6] << 8) | r1[0];
    scal[0] = 0.5f * (__uint_as_float(v1) + __uint_as_float(v2));  // sigma
  }
  // ---- class/domain bucketing ----
  __shared__ unsigned cl[64];
  __shared__ unsigned bs2[64];
  __shared__ unsigned cur[64];
  if (tid < 64) cl[tid] = 0;
  __syncthreads();
  for (int i = tid; i < N_TOT; i += 256) atomicAdd(&cl[y[i] * 2 + l[i]], 1u);
  __syncthreads();
  if (tid == 0) {
    unsigned run = 0;
    for (int b2 = 0; b2 < 62; b2++) { bs2[b2] = run; run += cl[b2]; }
    unsigned run2 = 0, cnt0 = 0;
    for (int c = 0; c < NCLASS; c++) {
      int n = (int)(cl[2 * c] + cl[2 * c + 1]);
      meta[c] = n; meta[32 + c] = (int)cl[2 * c]; meta[64 + c] = (int)bs2[2 * c];
      meta[96 + c] = (int)run2; run2 += (unsigned)(n * n);
      cnt0 += cl[2 * c];
    }
    scal[1] = (float)((double)cnt0 / (4096.0 * 4096.0));
    scal[2] = (float)((double)(N_TOT - cnt0) / (4096.0 * 4096.0));
  }
  __syncthreads();
  if (tid < 64) cur[tid] = bs2[tid];
  __syncthreads();
  for (int i = tid; i < N_TOT; i += 256) {
    int b2 = y[i] * 2 + l[i];
    unsigned pos = atomicAdd(&cur[b2], 1u);
    perm[pos] = i;
  }
}

// ------- build per-class K blocks: lower-triangle tiles + mirrored store -------
__global__ __launch_bounds__(256) void build_k(const float* __restrict__ sf, const float* __restrict__ tf,
                                               const float* __restrict__ xn, const int* __restrict__ perm,
                                               const int* __restrict__ meta, const float* __restrict__ scal,
                                               float* __restrict__ gK) {
  const int c = blockIdx.z;
  const int n = meta[c];
  const int cs = meta[64 + c];
  const int bo = meta[96 + c];
  const int T = (n + 15) >> 4;
  int b = blockIdx.x;
  if (b >= T * (T + 1) / 2) return;
  int by = (int)((sqrtf(8.f * (float)b + 1.f) - 1.f) * 0.5f);
  while ((by + 1) * (by + 2) / 2 <= b) ++by;
  while (by * (by + 1) / 2 > b) --by;
  int bx = b - by * (by + 1) / 2;
  const int i0 = by * 16, j0 = bx * 16;
  const int tx = threadIdx.x, ty = threadIdx.y;
  __shared__ float As[16][260];
  __shared__ float Bs[16][260];
  __shared__ float ot[16][17];
  __shared__ int ra[16];
  __shared__ int rb[16];
  int tid = ty * 16 + tx;
  if (tid < 16) { int il = i0 + tid; ra[tid] = (il < n) ? perm[cs + il] : -1; }
  else if (tid < 32) { int jl = j0 + tid - 16; rb[tid - 16] = (jl < n) ? perm[cs + jl] : -1; }
  __syncthreads();
  for (int e = tid; e < 1024; e += 256) {
    int r = e >> 6, q = e & 63;
    int g = ra[r];
    if (g >= 0) {
      const float* src = (g < N_SRC) ? (sf + (size_t)g * DIMF) : (tf + (size_t)(g - N_SRC) * DIMF);
      ((float4*)&As[r][q * 4])[0] = ((const float4*)src)[q];
    }
    int g2 = rb[r];
    if (g2 >= 0) {
      const float* src = (g2 < N_SRC) ? (sf + (size_t)g2 * DIMF) : (tf + (size_t)(g2 - N_SRC) * DIMF);
      ((float4*)&Bs[r][q * 4])[0] = ((const float4*)src)[q];
    }
  }
  __syncthreads();
  int il = i0 + ty, jl = j0 + tx;
  float val = 0.f;
  if (il < n && jl < n) {
    float dot = 0.f;
    const float4* a4 = (const float4*)&As[ty][0];
    const float4* b4 = (const float4*)&Bs[tx][0];
#pragma unroll 16
    for (int q = 0; q < 64; q++) {
      float4 a = a4[q], b2 = b4[q];
      dot += a.x * b2.x + a.y * b2.y + a.z * b2.z + a.w * b2.w;
    }
    int gi = ra[ty], gj = rb[tx];
    float d = xn[gi] + xn[gj] - 2.f * dot;
    val = expf(-d / scal[0]);
    gK[(size_t)bo + (size_t)il * n + jl] = val;
  }
  ot[ty][tx] = val;
  __syncthreads();
  if (by != bx) {
    int il2 = j0 + ty, jl2 = i0 + tx;
    if (il2 < n && jl2 < n) gK[(size_t)bo + (size_t)il2 * n + jl2] = ot[tx][ty];
  }
}

// ---------------- per-(class,domain) Newton-PCG + fused final (256 threads) ----------------
// R12: merged Av+S+obj phase (1 barrier saved/iter), gtp via CG identity
// g^T x = -sum(alpha_k rz_k) (whole SumMax reduction phase removed), frozen
// Jacobi, it=0 shortcut, inexact CG tol. Final eval exact f32 from global K.
__global__ __launch_bounds__(256) void solver_k(const float* __restrict__ gK, const int* __restrict__ meta,
                                                const float* __restrict__ scal, double* __restrict__ acc,
                                                unsigned* __restrict__ tick, float* __restrict__ out) {
  const int c = blockIdx.x >> 1, d = blockIdx.x & 1;
  const int n = meta[c];
  const int m0 = meta[32 + c];
  const int m = d ? (n - m0) : m0;
  const int c0 = d ? m0 : 0;
  const int bo = meta[96 + c];
  const float gamma = scal[1 + d];
  const int tid = threadIdx.x;
  const int wv = tid >> 6, lane = tid & 63;

  __shared__ unsigned short Wl[MAXW * WPAD];   // 51072 B
  __shared__ float pS[4 * MAXM];
  __shared__ float pD[4 * MAXM];
  __shared__ float Av[MAXW];
  __shared__ float Sv[MAXW];
  __shared__ float Uv[MAXW];
  __shared__ float Bq[MAXW];
  __shared__ float bc[MAXM];
  __shared__ float th[MAXM + 1];
  __shared__ float gv[MAXM];
  __shared__ float dgv[MAXM];
  __shared__ float pv[MAXM + 1];
  __shared__ float rv[MAXM + 1];
  __shared__ float zv[MAXM + 1];
  __shared__ float xv[MAXM + 1];
  __shared__ double red[16];

  const float* K = gK + bo;
  const int st = n;
  const int mp2 = (m + 1) & ~1;
  const int iw0 = (n * wv) >> 2, iw1 = (n * (wv + 1)) >> 2;

  for (int i = tid >> 2; i < n; i += 64) {
    const float* Kr = K + (size_t)i * st + c0;
    unsigned short* Wr = Wl + i * WPAD;
    for (int j = (tid & 3); j < m; j += 4) {
      unsigned u = __float_as_uint(Kr[j]);
      u += 0x7fffu + ((u >> 16) & 1u);   // RNE to bf16
      Wr[j] = (unsigned short)(u >> 16);
    }
    if ((tid & 3) == 0 && (m & 1)) Wr[m] = 0;
  }
  {
    const int r0 = (m * wv) >> 2, r1 = (m * (wv + 1)) >> 2;
    for (int j = lane; j < m; j += 64) {
      const float* Kr = K + (size_t)(c0 + j) * st + c0;
      float s = 0.f;
      for (int r = r0; r < r1; r++) s += Kr[r];
      pS[wv * MAXM + j] = s;
    }
  }
  __syncthreads();
  for (int j = tid; j < mp2; j += 256) {
    if (j < m) bc[j] = (pS[j] + pS[MAXM + j] + pS[2 * MAXM + j] + pS[3 * MAXM + j]) * (1.0f / 4096.0f);
    th[j] = 0.f;
  }
  __syncthreads();

  for (int it = 0; it < 25; it++) {
    double o = 0.0;
    if (it == 0) {
      const float s0c = gamma * expf(-1.f);
      for (int i = tid; i < n; i += 256) { Av[i] = 0.f; Sv[i] = s0c; o += (double)s0c; }
    } else {
      // merged: Av matvec -> S -> obj contribution (no barrier inside)
      for (int i = tid; i < n; i += 256) {
        const unsigned short* Wr = Wl + i * WPAD;
        float a = 0.f;
#pragma unroll 4
        for (int j = 0; j < mp2; j += 2) {
          unsigned u = *(const unsigned*)(Wr + j);
          a += __uint_as_float(u << 16) * th[j]
             + __uint_as_float(u & 0xffff0000u) * th[j + 1];
        }
        Av[i] = a;
        float si = gamma * expf(fminf(a - 1.f, 30.f));
        Sv[i] = si; o += (double)si;
      }
      for (int j = tid; j < m; j += 256) {
        float t_ = th[j];
        o += (double)(-bc[j] * t_ + LAMBDA * t_ * t_);
      }
    }
    __syncthreads();
    // ---- gradient (+ Jacobi diag at it==0 only; frozen after) ----
    if (it == 0) {
      for (int j = lane; j < m; j += 64) {
        const unsigned short* Wc = Wl + j;
        float s_ = 0.f, ds_ = 0.f;
        int i = iw0;
        for (; i + 3 < iw1; i += 4) {
          float w0 = bf2f(Wc[(i + 0) * WPAD]), w1 = bf2f(Wc[(i + 1) * WPAD]);
          float w2 = bf2f(Wc[(i + 2) * WPAD]), w3 = bf2f(Wc[(i + 3) * WPAD]);
          float a0 = w0 * Sv[i], a1 = w1 * Sv[i + 1], a2 = w2 * Sv[i + 2], a3 = w3 * Sv[i + 3];
          s_ += a0 + a1 + a2 + a3;
          ds_ += a0 * w0 + a1 * w1 + a2 * w2 + a3 * w3;
        }
        for (; i < iw1; i++) { float w = bf2f(Wc[i * WPAD]); float a = w * Sv[i]; s_ += a; ds_ += a * w; }
        pS[wv * MAXM + j] = s_; pD[wv * MAXM + j] = ds_;
      }
    } else {
      for (int j = lane; j < m; j += 64) {
        const unsigned short* Wc = Wl + j;
        float s_ = 0.f;
        int i = iw0;
        for (; i + 3 < iw1; i += 4)
          s_ += bf2f(Wc[(i+0)*WPAD]) * Sv[i]   + bf2f(Wc[(i+1)*WPAD]) * Sv[i+1]
              + bf2f(Wc[(i+2)*WPAD]) * Sv[i+2] + bf2f(Wc[(i+3)*WPAD]) * Sv[i+3];
        for (; i < iw1; i++) s_ += bf2f(Wc[i * WPAD]) * Sv[i];
        pS[wv * MAXM + j] = s_;
      }
    }
    __syncthreads();
    double gm = 0.0;
    for (int j = tid; j < m; j += 256) {
      float s_ = pS[j] + pS[MAXM + j] + pS[2 * MAXM + j] + pS[3 * MAXM + j];
      if (it == 0) {
        float ds_ = pD[j] + pD[MAXM + j] + pD[2 * MAXM + j] + pD[3 * MAXM + j];
        dgv[j] = ds_ + 2.f * LAMBDA;
      }
      float g = s_ - bc[j] + 2.f * LAMBDA * th[j];
      gv[j] = g;
      double ag = fabs((double)g); if (ag > gm) gm = ag;
    }
    double obj, gmax;
    blockReduceSumMax(o, gm, red, obj, gmax);
    if (gmax < 1e-5) break;

    // ---- PCG solve H x = -g (frozen Jacobi precond), inexact-Newton tol ----
    const double tolf = (it == 0) ? 1e-2 : ((it == 1) ? 1e-3 : 1e-4);
    double rz = 0.0;
    for (int j = tid; j < mp2; j += 256) {
      float r0 = (j < m) ? -gv[j] : 0.f;
      float z0 = (j < m) ? r0 / dgv[j] : 0.f;
      rv[j] = r0; zv[j] = z0; pv[j] = z0; xv[j] = 0.f;
      rz += (double)r0 * (double)z0;
    }
    rz = blockReduceSum(rz, red);
    double rz0 = rz;
    double gtpacc = 0.0;   // block-uniform: sum of alpha_k * rz_k = -g^T x
    for (int cg = 0; cg < 12; cg++) {
      __syncthreads();
      for (int i = tid; i < n; i += 256) {
        const unsigned short* Wr = Wl + i * WPAD;
        float a = 0.f;
#pragma unroll 4
        for (int j = 0; j < mp2; j += 2) {
          unsigned u = *(const unsigned*)(Wr + j);
          a += __uint_as_float(u << 16) * pv[j]
             + __uint_as_float(u & 0xffff0000u) * pv[j + 1];
        }
        Uv[i] = a * Sv[i];
      }
      __syncthreads();
      for (int j = lane; j < m; j += 64) {
        const unsigned short* Wc = Wl + j;
        float q = 0.f;
        int i = iw0;
        for (; i + 3 < iw1; i += 4)
          q += bf2f(Wc[(i+0)*WPAD]) * Uv[i]   + bf2f(Wc[(i+1)*WPAD]) * Uv[i+1]
             + bf2f(Wc[(i+2)*WPAD]) * Uv[i+2] + bf2f(Wc[(i+3)*WPAD]) * Uv[i+3];
        for (; i < iw1; i++) q += bf2f(Wc[i * WPAD]) * Uv[i];
        pS[wv * MAXM + j] = q;
      }
      __syncthreads();
      double pq = 0.0;
      for (int j = tid; j < m; j += 256) {
        float q = pS[j] + pS[MAXM + j] + pS[2 * MAXM + j] + pS[3 * MAXM + j] + 2.f * LAMBDA * pv[j];
        Bq[j] = q;
        pq += (double)pv[j] * (double)q;
      }
      pq = blockReduceSum(pq, red);
      if (!(pq > 0.0)) break;
      float alpha = (float)(rz / pq);
      gtpacc += (double)alpha * rz;
      double rznew = 0.0;
      for (int j = tid; j < m; j += 256) {
        xv[j] += alpha * pv[j];
        float rn = rv[j] - alpha * Bq[j];
        rv[j] = rn;
        float zn = rn / dgv[j];
        zv[j] = zn;
        rznew += (double)rn * (double)zn;
      }
      rznew = blockReduceSum(rznew, red);
      if (rznew < tolf * rz0 || cg == 11) break;
      float beta = (float)(rznew / rz);
      for (int j = tid; j < m; j += 256) pv[j] = zv[j] + beta * pv[j];
      rz = rznew;
    }
    __syncthreads();
    // gtp = g^T x = -gtpacc (exact CG identity); no reduction phase needed
    double gtp = -gtpacc;
    if (!(gtp < 0.0)) break;   // no CG progress => converged/degenerate

    float t = 1.f;
    if (-gtp >= 1e-4) {
      for (int i = tid; i < n; i += 256) {
        const unsigned short* Wr = Wl + i * WPAD;
        float a = 0.f;
#pragma unroll 4
        for (int j = 0; j < mp2; j += 2) {
          unsigned u = *(const unsigned*)(Wr + j);
          a += __uint_as_float(u << 16) * xv[j]
             + __uint_as_float(u & 0xffff0000u) * xv[j + 1];
        }
        Bq[i] = a;
      }
      __syncthreads();
      for (int ls = 0; ls < 10; ls++) {
        double ol = 0.0;
        for (int i = tid; i < n; i += 256)
          ol += (double)(gamma * expf(fminf(Av[i] + t * Bq[i] - 1.f, 30.f)));
        for (int j = tid; j < m; j += 256) {
          float tj = th[j] + t * xv[j];
          ol += (double)(-bc[j] * tj + LAMBDA * tj * tj);
        }
        double ot2 = blockReduceSum(ol, red);
        if (ot2 <= obj + 1e-4 * (double)t * gtp) break;
        t *= 0.5f;
      }
    }
    for (int j = tid; j < mp2; j += 256) th[j] += t * xv[j];
    __syncthreads();
  }

  // ---- final exact f32 evaluation (global K, f32 theta) ----
  __syncthreads();
  for (int i = tid; i < n; i += 256) {
    const float* Kr = K + (size_t)i * st + c0;
    float a = 0.f;
    int j = 0;
    for (; j + 7 < m; j += 8)
      a += th[j] * Kr[j] + th[j+1] * Kr[j+1] + th[j+2] * Kr[j+2] + th[j+3] * Kr[j+3]
         + th[j+4] * Kr[j+4] + th[j+5] * Kr[j+5] + th[j+6] * Kr[j+6] + th[j+7] * Kr[j+7];
    for (; j < m; j++) a += th[j] * Kr[j];
    Av[i] = a;
  }
  __syncthreads();
  double t1l = 0.0, t2l = 0.0;
  for (int i = tid; i < n; i += 256) t2l += (double)(gamma * expf(fminf(Av[i] - 1.f, 30.f)));
  for (int j = tid; j < m; j += 256) t1l += (double)(bc[j] * th[j]);
  double t1 = blockReduceSum(t1l, red);
  double t2 = blockReduceSum(t2l, red);
  if (tid == 0) {
    atomicAdd(&acc[0], t1);
    atomicAdd(&acc[1], t2);
    __threadfence();
    unsigned old = __hip_atomic_fetch_add(&tick[0], 1u, __ATOMIC_ACQ_REL, __HIP_MEMORY_SCOPE_AGENT);
    if (old == 61u) {
      double a0 = __hip_atomic_load(&acc[0], __ATOMIC_RELAXED, __HIP_MEMORY_SCOPE_AGENT);
      double a1 = __hip_atomic_load(&acc[1], __ATOMIC_RELAXED, __HIP_MEMORY_SCOPE_AGENT);
      out[0] = (float)(a0 - a1);
    }
  }
}

// ---------------- launcher ----------------
extern "C" void kernel_launch(void* const* d_in, const int* in_sizes, int n_in,
                              void* d_out, int out_size, void* d_ws, size_t ws_size,
                              hipStream_t stream) {
  const float* sf = (const float*)d_in[0];
  const float* tf = (const float*)d_in[1];
  const int* y = (const int*)d_in[2];
  const int* l = (const int*)d_in[3];
  char* ws = (char*)d_ws;

  double*   acc    = (double*)(ws + WS_ACC);
  unsigned* hist0  = (unsigned*)(ws + WS_HIST0);
  unsigned* histA  = (unsigned*)(ws + WS_HISTA);
  unsigned* histB  = (unsigned*)(ws + WS_HISTB);
  unsigned* h2A    = (unsigned*)(ws + WS_H2A);
  unsigned* h2B    = (unsigned*)(ws + WS_H2B);
  unsigned* state  = (unsigned*)(ws + WS_STATE);
  unsigned* tick   = (unsigned*)(ws + WS_TICK);
  int*      meta   = (int*)(ws + WS_META);
  float*    scal   = (float*)(ws + WS_SCAL);
  int*      perm   = (int*)(ws + WS_PERM);
  float*    xnp    = (float*)(ws + WS_XN);
  float*    Ds     = (float*)(ws + WS_DS);
  float*    gK     = (float*)(ws + WS_KBLK);

  hipMemsetAsync(d_ws, 0, ZERO_BYTES, stream);
  hipLaunchKernelGGL(xn_kernel, dim3(1024), dim3(256), 0, stream, sf, tf, xnp);
  hipLaunchKernelGGL(dist_k, dim3(528), dim3(16, 16), 0, stream, sf, xnp, Ds, hist0);
  hipLaunchKernelGGL(scan0_k, dim3(1), dim3(256), 0, stream, hist0, state);
  hipLaunchKernelGGL(hist1_k, dim3(512), dim3(256), 0, stream, Ds, state, histA, histB);
  hipLaunchKernelGGL(scan1_k, dim3(1), dim3(256), 0, stream, histA, histB, state);
  hipLaunchKernelGGL(hist2_k, dim3(512), dim3(256), 0, stream, Ds, state, h2A, h2B);
  hipLaunchKernelGGL(scan2b_k, dim3(1), dim3(256), 0, stream, h2A, h2B, state, scal, y, l, perm, meta);
  hipLaunchKernelGGL(build_k, dim3(105, 1, NCLASS), dim3(16, 16), 0, stream, sf, tf, xnp, perm, meta, scal, gK);
  hipLaunchKernelGGL(solver_k, dim3(62), dim3(256), 0, stream, gK, meta, scal, acc, tick, (float*)d_out);
}

// Round 13
// 236.535 us; speedup vs baseline: 1.2545x; 1.0078x over previous
//
#include <hip/hip_runtime.h>
#include <math.h>

#define N_TOT   4096
#define N_SRC   2048
#define DIMF    256
#define NCLASS  31
#define LAMBDA  0.01f

// median target ranks among the 2,096,128 strict-lower-triangle values.
#define K_TRI1  1048063LL
#define K_TRI2  1048064LL

// ---- ws layout (bytes) ----
#define WS_ACC    0           // 2 doubles
#define WS_HIST0  64          // 4096 u32
#define WS_HISTA  16448       // 4096 u32
#define WS_HISTB  32832       // 4096 u32
#define WS_H2A    49216       // 256 u32
#define WS_H2B    50240       // 256 u32
#define WS_STATE  51264       // 64 u32 (st[0..7])
#define WS_TICK   51520       // 4 u32 (solver final ticket)
#define WS_META   52288       // 128 i32: ncls[32], m0c[32], cstart[32], blkoff[32]
#define WS_SCAL   52800       // 16 f32: [0]=sigma, [1]=gamma0, [2]=gamma1
#define ZERO_BYTES 53248
#define WS_PERM   53248       // 4096 i32
#define WS_XN     69632       // 4096 f32
#define WS_DS     1048576     // 2048*2048 f32 (lower triangle used)
#define WS_KBLK   17825792    // class K blocks (8 MB budget)

#define MAXW 224
#define MAXM 112
#define WPAD 114   // u16 row stride = 57 dwords (odd -> conflict-free rows & cols)

__device__ __forceinline__ float bf2f(unsigned short h) {
  return __uint_as_float(((unsigned)h) << 16);
}

// ---------------- reductions (256 threads) ----------------
__device__ __forceinline__ double blockReduceSum(double v, double* red) {
#pragma unroll
  for (int o = 32; o > 0; o >>= 1) v += __shfl_down(v, o, 64);
  int w = threadIdx.x >> 6, lane = threadIdx.x & 63;
  __syncthreads();
  if (lane == 0) red[w] = v;
  __syncthreads();
  return red[0] + red[1] + red[2] + red[3];
}

__device__ __forceinline__ void blockReduceSumMax(double s, double mx, double* red,
                                                  double& os, double& om) {
#pragma unroll
  for (int o = 32; o > 0; o >>= 1) {
    s += __shfl_down(s, o, 64);
    double u = __shfl_down(mx, o, 64);
    mx = fmax(mx, u);
  }
  int w = threadIdx.x >> 6, lane = threadIdx.x & 63;
  __syncthreads();
  if (lane == 0) { red[w] = s; red[4 + w] = mx; }
  __syncthreads();
  os = red[0] + red[1] + red[2] + red[3];
  om = fmax(fmax(red[4], red[5]), fmax(red[6], red[7]));
}

// scan over histogram (256 threads)
__device__ void scan_find(const unsigned* hist, int nbins, long long k, unsigned* shOut) {
  __shared__ long long tsum[256];
  int tid = threadIdx.x;
  int per = nbins / 256;
  long long s = 0;
  for (int q = 0; q < per; q++) s += hist[tid * per + q];
  tsum[tid] = s;
  __syncthreads();
  if (tid == 0) {
    long long run = 0;
    for (int t = 0; t < 256; t++) { long long v = tsum[t]; tsum[t] = run; run += v; }
  }
  __syncthreads();
  long long run = tsum[tid];
  for (int q = 0; q < per; q++) {
    unsigned c = hist[tid * per + q];
    if (k >= run && k < run + (long long)c) { shOut[0] = (unsigned)(tid * per + q); shOut[1] = (unsigned)(k - run); }
    run += c;
  }
  __syncthreads();
}

// ---------------- row norms (coalesced, trivial) ----------------
__global__ __launch_bounds__(256) void xn_kernel(const float* __restrict__ sf,
                                                 const float* __restrict__ tf,
                                                 float* __restrict__ xn) {
  int wid = threadIdx.x >> 6, lane = threadIdx.x & 63;
  int row = blockIdx.x * 4 + wid;
  const float* src = (row < N_SRC) ? (sf + (size_t)row * DIMF) : (tf + (size_t)(row - N_SRC) * DIMF);
  float4 v = ((const float4*)src)[lane];
  float s = v.x * v.x + v.y * v.y + v.z * v.z + v.w * v.w;
#pragma unroll
  for (int o = 32; o > 0; o >>= 1) s += __shfl_down(s, o, 64);
  if (lane == 0) xn[row] = s;
}

// ------- source pairwise sq-dists (triangle), pipelined staging, fused hist0 -------
// (R10-proven version: KC=16, 28 KB LDS, high occupancy)
__global__ __launch_bounds__(256) void dist_k(const float* __restrict__ sf,
                                              const float* __restrict__ xn,
                                              float* __restrict__ Ds,
                                              unsigned* __restrict__ h) {
  __shared__ float As[16][68];
  __shared__ float Bs[16][68];
  __shared__ unsigned lh[4096];
  const int tx = threadIdx.x, ty = threadIdx.y;
  const int tid = ty * 16 + tx;
  for (int q = tid; q < 4096; q += 256) lh[q] = 0;
  // triangle block index -> (by,bx), by >= bx
  int b = blockIdx.x;
  int by = (int)((sqrtf(8.f * (float)b + 1.f) - 1.f) * 0.5f);
  while ((by + 1) * (by + 2) / 2 <= b) ++by;
  while (by * (by + 1) / 2 > b) --by;
  int bx = b - by * (by + 1) / 2;
  const int R = by * 64, C = bx * 64;
  const int si = tid >> 2, sq = tid & 3;
  // software-pipelined staging: prefetch kc+16 into regs during compute of kc
  float4 va = ((const float4*)(sf + (size_t)(R + si) * 256 + 0))[sq];
  float4 vb = ((const float4*)(sf + (size_t)(C + si) * 256 + 0))[sq];
  float acc[4][4] = {};
  for (int kc = 0; kc < 256; kc += 16) {
    As[sq * 4 + 0][si] = va.x; As[sq * 4 + 1][si] = va.y; As[sq * 4 + 2][si] = va.z; As[sq * 4 + 3][si] = va.w;
    Bs[sq * 4 + 0][si] = vb.x; Bs[sq * 4 + 1][si] = vb.y; Bs[sq * 4 + 2][si] = vb.z; Bs[sq * 4 + 3][si] = vb.w;
    __syncthreads();
    if (kc + 16 < 256) {
      va = ((const float4*)(sf + (size_t)(R + si) * 256 + kc + 16))[sq];
      vb = ((const float4*)(sf + (size_t)(C + si) * 256 + kc + 16))[sq];
    }
#pragma unroll
    for (int k = 0; k < 16; k++) {
      float4 a = *(const float4*)&As[k][ty * 4];
      float4 b2 = *(const float4*)&Bs[k][tx * 4];
      acc[0][0] += a.x * b2.x; acc[0][1] += a.x * b2.y; acc[0][2] += a.x * b2.z; acc[0][3] += a.x * b2.w;
      acc[1][0] += a.y * b2.x; acc[1][1] += a.y * b2.y; acc[1][2] += a.y * b2.z; acc[1][3] += a.y * b2.w;
      acc[2][0] += a.z * b2.x; acc[2][1] += a.z * b2.y; acc[2][2] += a.z * b2.z; acc[2][3] += a.z * b2.w;
      acc[3][0] += a.w * b2.x; acc[3][1] += a.w * b2.y; acc[3][2] += a.w * b2.z; acc[3][3] += a.w * b2.w;
    }
    __syncthreads();
  }
  int jbase = C + tx * 4;
  float xnj0 = xn[jbase + 0], xnj1 = xn[jbase + 1], xnj2 = xn[jbase + 2], xnj3 = xn[jbase + 3];
#pragma unroll
  for (int r = 0; r < 4; r++) {
    int i = R + ty * 4 + r;
    float xni = xn[i];
    float v[4];
    v[0] = fmaxf(xni + xnj0 - 2.f * acc[r][0], 0.f);
    v[1] = fmaxf(xni + xnj1 - 2.f * acc[r][1], 0.f);
    v[2] = fmaxf(xni + xnj2 - 2.f * acc[r][2], 0.f);
    v[3] = fmaxf(xni + xnj3 - 2.f * acc[r][3], 0.f);
    if (jbase + 3 < i) {
      float4 o; o.x = v[0]; o.y = v[1]; o.z = v[2]; o.w = v[3];
      ((float4*)&Ds[(size_t)i * 2048 + jbase])[0] = o;
      atomicAdd(&lh[__float_as_uint(v[0]) >> 20], 1u);
      atomicAdd(&lh[__float_as_uint(v[1]) >> 20], 1u);
      atomicAdd(&lh[__float_as_uint(v[2]) >> 20], 1u);
      atomicAdd(&lh[__float_as_uint(v[3]) >> 20], 1u);
    } else {
#pragma unroll
      for (int k = 0; k < 4; k++) {
        if (jbase + k < i) {
          Ds[(size_t)i * 2048 + jbase + k] = v[k];
          atomicAdd(&lh[__float_as_uint(v[k]) >> 20], 1u);
        }
      }
    }
  }
  __syncthreads();
  for (int q = tid; q < 4096; q += 256) if (lh[q]) atomicAdd(&h[q], lh[q]);
}

__global__ __launch_bounds__(256) void scan0_k(const unsigned* __restrict__ h, unsigned* __restrict__ st) {
  __shared__ unsigned r0[2];
  __shared__ unsigned r1[2];
  scan_find(h, 4096, K_TRI1, r0);
  scan_find(h, 4096, K_TRI2, r1);
  if (threadIdx.x == 0) { st[0] = r0[0]; st[1] = r0[1]; st[2] = r1[0]; st[3] = r1[1]; }
}

// ---------------- radix pass 1 (triangle reads, balanced rows) ----------------
__global__ __launch_bounds__(256) void hist1_k(const float* __restrict__ Ds, const unsigned* __restrict__ st,
                                               unsigned* __restrict__ hA, unsigned* __restrict__ hB) {
  __shared__ unsigned lA[4096];
  __shared__ unsigned lB[4096];
  for (int i = threadIdx.x; i < 4096; i += 256) { lA[i] = 0; lB[i] = 0; }
  __syncthreads();
  unsigned s0 = st[0], s1 = st[2];
  int gw = (blockIdx.x * 256 + threadIdx.x) >> 6;
  // balance: pair long rows with short rows inside each block
  int rowi = (gw & 1) ? (2047 - (gw >> 1)) : (gw >> 1);
  int lane = threadIdx.x & 63;
  const float* row = Ds + (size_t)rowi * 2048;
  for (int j = lane; j < rowi; j += 64) {
    unsigned u = __float_as_uint(row[j]);
    unsigned hi = u >> 20, mid = (u >> 8) & 0xFFFu;
    if (hi == s0) atomicAdd(&lA[mid], 1u);
    if (hi == s1) atomicAdd(&lB[mid], 1u);
  }
  __syncthreads();
  for (int i = threadIdx.x; i < 4096; i += 256) {
    if (lA[i]) atomicAdd(&hA[i], lA[i]);
    if (lB[i]) atomicAdd(&hB[i], lB[i]);
  }
}

__global__ __launch_bounds__(256) void scan1_k(const unsigned* __restrict__ hA, const unsigned* __restrict__ hB,
                                               unsigned* __restrict__ st) {
  __shared__ unsigned r0[2];
  __shared__ unsigned r1[2];
  long long kA = (long long)st[1];
  long long kB = (long long)st[3];
  scan_find(hA, 4096, kA, r0);
  scan_find(hB, 4096, kB, r1);
  if (threadIdx.x == 0) { st[4] = r0[0]; st[5] = r0[1]; st[6] = r1[0]; st[7] = r1[1]; }
}

// ---------------- radix pass 2 (triangle reads, balanced rows) ----------------
__global__ __launch_bounds__(256) void hist2_k(const float* __restrict__ Ds, const unsigned* __restrict__ st,
                                               unsigned* __restrict__ hA, unsigned* __restrict__ hB) {
  __shared__ unsigned lA[256];
  __shared__ unsigned lB[256];
  lA[threadIdx.x] = 0; lB[threadIdx.x] = 0;
  __syncthreads();
  unsigned p0 = (st[0] << 12) | st[4];
  unsigned p1 = (st[2] << 12) | st[6];
  int gw = (blockIdx.x * 256 + threadIdx.x) >> 6;
  int rowi = (gw & 1) ? (2047 - (gw >> 1)) : (gw >> 1);
  int lane = threadIdx.x & 63;
  const float* row = Ds + (size_t)rowi * 2048;
  for (int j = lane; j < rowi; j += 64) {
    unsigned u = __float_as_uint(row[j]);
    unsigned pre = u >> 8;
    if (pre == p0) atomicAdd(&lA[u & 0xFFu], 1u);
    if (pre == p1) atomicAdd(&lB[u & 0xFFu], 1u);
  }
  __syncthreads();
  if (lA[threadIdx.x]) atomicAdd(&hA[threadIdx.x], lA[threadIdx.x]);
  if (lB[threadIdx.x]) atomicAdd(&hB[threadIdx.x], lB[threadIdx.x]);
}

// ------- scan2 (sigma) + class/domain bucketing, single block -------
__global__ __launch_bounds__(256) void scan2b_k(const unsigned* __restrict__ hA, const unsigned* __restrict__ hB,
                                                const unsigned* __restrict__ st, float* __restrict__ scal,
                                                const int* __restrict__ y, const int* __restrict__ l,
                                                int* __restrict__ perm, int* __restrict__ meta) {
  int tid = threadIdx.x;
  __shared__ unsigned r0[2];
  __shared__ unsigned r1[2];
  scan_find(hA, 256, (long long)st[5], r0);
  scan_find(hB, 256, (long long)st[7], r1);
  if (tid == 0) {
    unsigned v1 = (st[0] << 20) | (st[4] << 8) | r0[0];
    unsigned v2 = (st[2] << 20) | (st[6] << 8) | r1[0];
    scal[0] = 0.5f * (__uint_as_float(v1) + __uint_as_float(v2));  // sigma
  }
  // ---- class/domain bucketing ----
  __shared__ unsigned cl[64];
  __shared__ unsigned bs2[64];
  __shared__ unsigned cur[64];
  if (tid < 64) cl[tid] = 0;
  __syncthreads();
  for (int i = tid; i < N_TOT; i += 256) atomicAdd(&cl[y[i] * 2 + l[i]], 1u);
  __syncthreads();
  if (tid == 0) {
    unsigned run = 0;
    for (int b2 = 0; b2 < 62; b2++) { bs2[b2] = run; run += cl[b2]; }
    unsigned run2 = 0, cnt0 = 0;
    for (int c = 0; c < NCLASS; c++) {
      int n = (int)(cl[2 * c] + cl[2 * c + 1]);
      meta[c] = n; meta[32 + c] = (int)cl[2 * c]; meta[64 + c] = (int)bs2[2 * c];
      meta[96 + c] = (int)run2; run2 += (unsigned)(n * n);
      cnt0 += cl[2 * c];
    }
    scal[1] = (float)((double)cnt0 / (4096.0 * 4096.0));
    scal[2] = (float)((double)(N_TOT - cnt0) / (4096.0 * 4096.0));
  }
  __syncthreads();
  if (tid < 64) cur[tid] = bs2[tid];
  __syncthreads();
  for (int i = tid; i < N_TOT; i += 256) {
    int b2 = y[i] * 2 + l[i];
    unsigned pos = atomicAdd(&cur[b2], 1u);
    perm[pos] = i;
  }
}

// ------- build per-class K blocks: lower-triangle tiles + mirrored store -------
__global__ __launch_bounds__(256) void build_k(const float* __restrict__ sf, const float* __restrict__ tf,
                                               const float* __restrict__ xn, const int* __restrict__ perm,
                                               const int* __restrict__ meta, const float* __restrict__ scal,
                                               float* __restrict__ gK) {
  const int c = blockIdx.z;
  const int n = meta[c];
  const int cs = meta[64 + c];
  const int bo = meta[96 + c];
  const int T = (n + 15) >> 4;
  int b = blockIdx.x;
  if (b >= T * (T + 1) / 2) return;
  int by = (int)((sqrtf(8.f * (float)b + 1.f) - 1.f) * 0.5f);
  while ((by + 1) * (by + 2) / 2 <= b) ++by;
  while (by * (by + 1) / 2 > b) --by;
  int bx = b - by * (by + 1) / 2;
  const int i0 = by * 16, j0 = bx * 16;
  const int tx = threadIdx.x, ty = threadIdx.y;
  __shared__ float As[16][260];
  __shared__ float Bs[16][260];
  __shared__ float ot[16][17];
  __shared__ int ra[16];
  __shared__ int rb[16];
  int tid = ty * 16 + tx;
  if (tid < 16) { int il = i0 + tid; ra[tid] = (il < n) ? perm[cs + il] : -1; }
  else if (tid < 32) { int jl = j0 + tid - 16; rb[tid - 16] = (jl < n) ? perm[cs + jl] : -1; }
  __syncthreads();
  for (int e = tid; e < 1024; e += 256) {
    int r = e >> 6, q = e & 63;
    int g = ra[r];
    if (g >= 0) {
      const float* src = (g < N_SRC) ? (sf + (size_t)g * DIMF) : (tf + (size_t)(g - N_SRC) * DIMF);
      ((float4*)&As[r][q * 4])[0] = ((const float4*)src)[q];
    }
    int g2 = rb[r];
    if (g2 >= 0) {
      const float* src = (g2 < N_SRC) ? (sf + (size_t)g2 * DIMF) : (tf + (size_t)(g2 - N_SRC) * DIMF);
      ((float4*)&Bs[r][q * 4])[0] = ((const float4*)src)[q];
    }
  }
  __syncthreads();
  int il = i0 + ty, jl = j0 + tx;
  float val = 0.f;
  if (il < n && jl < n) {
    float dot = 0.f;
    const float4* a4 = (const float4*)&As[ty][0];
    const float4* b4 = (const float4*)&Bs[tx][0];
#pragma unroll 16
    for (int q = 0; q < 64; q++) {
      float4 a = a4[q], b2 = b4[q];
      dot += a.x * b2.x + a.y * b2.y + a.z * b2.z + a.w * b2.w;
    }
    int gi = ra[ty], gj = rb[tx];
    float d = xn[gi] + xn[gj] - 2.f * dot;
    val = expf(-d / scal[0]);
    gK[(size_t)bo + (size_t)il * n + jl] = val;
  }
  ot[ty][tx] = val;
  __syncthreads();
  if (by != bx) {
    int il2 = j0 + ty, jl2 = i0 + tx;
    if (il2 < n && jl2 < n) gK[(size_t)bo + (size_t)il2 * n + jl2] = ot[tx][ty];
  }
}

// ---------------- per-(class,domain) Newton-PCG + fused final (256 threads) ----------------
// R12-proven solver: merged Av+S+obj phase, gtp via CG identity, frozen Jacobi,
// it=0 shortcut, inexact CG tol. Final eval exact f32 from global K.
__global__ __launch_bounds__(256) void solver_k(const float* __restrict__ gK, const int* __restrict__ meta,
                                                const float* __restrict__ scal, double* __restrict__ acc,
                                                unsigned* __restrict__ tick, float* __restrict__ out) {
  const int c = blockIdx.x >> 1, d = blockIdx.x & 1;
  const int n = meta[c];
  const int m0 = meta[32 + c];
  const int m = d ? (n - m0) : m0;
  const int c0 = d ? m0 : 0;
  const int bo = meta[96 + c];
  const float gamma = scal[1 + d];
  const int tid = threadIdx.x;
  const int wv = tid >> 6, lane = tid & 63;

  __shared__ unsigned short Wl[MAXW * WPAD];   // 51072 B
  __shared__ float pS[4 * MAXM];
  __shared__ float pD[4 * MAXM];
  __shared__ float Av[MAXW];
  __shared__ float Sv[MAXW];
  __shared__ float Uv[MAXW];
  __shared__ float Bq[MAXW];
  __shared__ float bc[MAXM];
  __shared__ float th[MAXM + 1];
  __shared__ float gv[MAXM];
  __shared__ float dgv[MAXM];
  __shared__ float pv[MAXM + 1];
  __shared__ float rv[MAXM + 1];
  __shared__ float zv[MAXM + 1];
  __shared__ float xv[MAXM + 1];
  __shared__ double red[16];

  const float* K = gK + bo;
  const int st = n;
  const int mp2 = (m + 1) & ~1;
  const int iw0 = (n * wv) >> 2, iw1 = (n * (wv + 1)) >> 2;

  for (int i = tid >> 2; i < n; i += 64) {
    const float* Kr = K + (size_t)i * st + c0;
    unsigned short* Wr = Wl + i * WPAD;
    for (int j = (tid & 3); j < m; j += 4) {
      unsigned u = __float_as_uint(Kr[j]);
      u += 0x7fffu + ((u >> 16) & 1u);   // RNE to bf16
      Wr[j] = (unsigned short)(u >> 16);
    }
    if ((tid & 3) == 0 && (m & 1)) Wr[m] = 0;
  }
  {
    const int r0 = (m * wv) >> 2, r1 = (m * (wv + 1)) >> 2;
    for (int j = lane; j < m; j += 64) {
      const float* Kr = K + (size_t)(c0 + j) * st + c0;
      float s = 0.f;
      for (int r = r0; r < r1; r++) s += Kr[r];
      pS[wv * MAXM + j] = s;
    }
  }
  __syncthreads();
  for (int j = tid; j < mp2; j += 256) {
    if (j < m) bc[j] = (pS[j] + pS[MAXM + j] + pS[2 * MAXM + j] + pS[3 * MAXM + j]) * (1.0f / 4096.0f);
    th[j] = 0.f;
  }
  __syncthreads();

  for (int it = 0; it < 25; it++) {
    double o = 0.0;
    if (it == 0) {
      const float s0c = gamma * expf(-1.f);
      for (int i = tid; i < n; i += 256) { Av[i] = 0.f; Sv[i] = s0c; o += (double)s0c; }
    } else {
      // merged: Av matvec -> S -> obj contribution (no barrier inside)
      for (int i = tid; i < n; i += 256) {
        const unsigned short* Wr = Wl + i * WPAD;
        float a = 0.f;
#pragma unroll 4
        for (int j = 0; j < mp2; j += 2) {
          unsigned u = *(const unsigned*)(Wr + j);
          a += __uint_as_float(u << 16) * th[j]
             + __uint_as_float(u & 0xffff0000u) * th[j + 1];
        }
        Av[i] = a;
        float si = gamma * expf(fminf(a - 1.f, 30.f));
        Sv[i] = si; o += (double)si;
      }
      for (int j = tid; j < m; j += 256) {
        float t_ = th[j];
        o += (double)(-bc[j] * t_ + LAMBDA * t_ * t_);
      }
    }
    __syncthreads();
    // ---- gradient (+ Jacobi diag at it==0 only; frozen after) ----
    if (it == 0) {
      for (int j = lane; j < m; j += 64) {
        const unsigned short* Wc = Wl + j;
        float s_ = 0.f, ds_ = 0.f;
        int i = iw0;
        for (; i + 3 < iw1; i += 4) {
          float w0 = bf2f(Wc[(i + 0) * WPAD]), w1 = bf2f(Wc[(i + 1) * WPAD]);
          float w2 = bf2f(Wc[(i + 2) * WPAD]), w3 = bf2f(Wc[(i + 3) * WPAD]);
          float a0 = w0 * Sv[i], a1 = w1 * Sv[i + 1], a2 = w2 * Sv[i + 2], a3 = w3 * Sv[i + 3];
          s_ += a0 + a1 + a2 + a3;
          ds_ += a0 * w0 + a1 * w1 + a2 * w2 + a3 * w3;
        }
        for (; i < iw1; i++) { float w = bf2f(Wc[i * WPAD]); float a = w * Sv[i]; s_ += a; ds_ += a * w; }
        pS[wv * MAXM + j] = s_; pD[wv * MAXM + j] = ds_;
      }
    } else {
      for (int j = lane; j < m; j += 64) {
        const unsigned short* Wc = Wl + j;
        float s_ = 0.f;
        int i = iw0;
        for (; i + 3 < iw1; i += 4)
          s_ += bf2f(Wc[(i+0)*WPAD]) * Sv[i]   + bf2f(Wc[(i+1)*WPAD]) * Sv[i+1]
              + bf2f(Wc[(i+2)*WPAD]) * Sv[i+2] + bf2f(Wc[(i+3)*WPAD]) * Sv[i+3];
        for (; i < iw1; i++) s_ += bf2f(Wc[i * WPAD]) * Sv[i];
        pS[wv * MAXM + j] = s_;
      }
    }
    __syncthreads();
    double gm = 0.0;
    for (int j = tid; j < m; j += 256) {
      float s_ = pS[j] + pS[MAXM + j] + pS[2 * MAXM + j] + pS[3 * MAXM + j];
      if (it == 0) {
        float ds_ = pD[j] + pD[MAXM + j] + pD[2 * MAXM + j] + pD[3 * MAXM + j];
        dgv[j] = ds_ + 2.f * LAMBDA;
      }
      float g = s_ - bc[j] + 2.f * LAMBDA * th[j];
      gv[j] = g;
      double ag = fabs((double)g); if (ag > gm) gm = ag;
    }
    double obj, gmax;
    blockReduceSumMax(o, gm, red, obj, gmax);
    if (gmax < 1e-5) break;

    // ---- PCG solve H x = -g (frozen Jacobi precond), inexact-Newton tol ----
    const double tolf = (it == 0) ? 1e-2 : ((it == 1) ? 1e-3 : 1e-4);
    double rz = 0.0;
    for (int j = tid; j < mp2; j += 256) {
      float r0 = (j < m) ? -gv[j] : 0.f;
      float z0 = (j < m) ? r0 / dgv[j] : 0.f;
      rv[j] = r0; zv[j] = z0; pv[j] = z0; xv[j] = 0.f;
      rz += (double)r0 * (double)z0;
    }
    rz = blockReduceSum(rz, red);
    double rz0 = rz;
    double gtpacc = 0.0;   // block-uniform: sum of alpha_k * rz_k = -g^T x
    for (int cg = 0; cg < 12; cg++) {
      __syncthreads();
      for (int i = tid; i < n; i += 256) {
        const unsigned short* Wr = Wl + i * WPAD;
        float a = 0.f;
#pragma unroll 4
        for (int j = 0; j < mp2; j += 2) {
          unsigned u = *(const unsigned*)(Wr + j);
          a += __uint_as_float(u << 16) * pv[j]
             + __uint_as_float(u & 0xffff0000u) * pv[j + 1];
        }
        Uv[i] = a * Sv[i];
      }
      __syncthreads();
      for (int j = lane; j < m; j += 64) {
        const unsigned short* Wc = Wl + j;
        float q = 0.f;
        int i = iw0;
        for (; i + 3 < iw1; i += 4)
          q += bf2f(Wc[(i+0)*WPAD]) * Uv[i]   + bf2f(Wc[(i+1)*WPAD]) * Uv[i+1]
             + bf2f(Wc[(i+2)*WPAD]) * Uv[i+2] + bf2f(Wc[(i+3)*WPAD]) * Uv[i+3];
        for (; i < iw1; i++) q += bf2f(Wc[i * WPAD]) * Uv[i];
        pS[wv * MAXM + j] = q;
      }
      __syncthreads();
      double pq = 0.0;
      for (int j = tid; j < m; j += 256) {
        float q = pS[j] + pS[MAXM + j] + pS[2 * MAXM + j] + pS[3 * MAXM + j] + 2.f * LAMBDA * pv[j];
        Bq[j] = q;
        pq += (double)pv[j] * (double)q;
      }
      pq = blockReduceSum(pq, red);
      if (!(pq > 0.0)) break;
      float alpha = (float)(rz / pq);
      gtpacc += (double)alpha * rz;
      double rznew = 0.0;
      for (int j = tid; j < m; j += 256) {
        xv[j] += alpha * pv[j];
        float rn = rv[j] - alpha * Bq[j];
        rv[j] = rn;
        float zn = rn / dgv[j];
        zv[j] = zn;
        rznew += (double)rn * (double)zn;
      }
      rznew = blockReduceSum(rznew, red);
      if (rznew < tolf * rz0 || cg == 11) break;
      float beta = (float)(rznew / rz);
      for (int j = tid; j < m; j += 256) pv[j] = zv[j] + beta * pv[j];
      rz = rznew;
    }
    __syncthreads();
    // gtp = g^T x = -gtpacc (exact CG identity); no reduction phase needed
    double gtp = -gtpacc;
    if (!(gtp < 0.0)) break;   // no CG progress => converged/degenerate

    float t = 1.f;
    if (-gtp >= 1e-4) {
      for (int i = tid; i < n; i += 256) {
        const unsigned short* Wr = Wl + i * WPAD;
        float a = 0.f;
#pragma unroll 4
        for (int j = 0; j < mp2; j += 2) {
          unsigned u = *(const unsigned*)(Wr + j);
          a += __uint_as_float(u << 16) * xv[j]
             + __uint_as_float(u & 0xffff0000u) * xv[j + 1];
        }
        Bq[i] = a;
      }
      __syncthreads();
      for (int ls = 0; ls < 10; ls++) {
        double ol = 0.0;
        for (int i = tid; i < n; i += 256)
          ol += (double)(gamma * expf(fminf(Av[i] + t * Bq[i] - 1.f, 30.f)));
        for (int j = tid; j < m; j += 256) {
          float tj = th[j] + t * xv[j];
          ol += (double)(-bc[j] * tj + LAMBDA * tj * tj);
        }
        double ot2 = blockReduceSum(ol, red);
        if (ot2 <= obj + 1e-4 * (double)t * gtp) break;
        t *= 0.5f;
      }
    }
    for (int j = tid; j < mp2; j += 256) th[j] += t * xv[j];
    __syncthreads();
  }

  // ---- final exact f32 evaluation (global K, f32 theta) ----
  __syncthreads();
  for (int i = tid; i < n; i += 256) {
    const float* Kr = K + (size_t)i * st + c0;
    float a = 0.f;
    int j = 0;
    for (; j + 7 < m; j += 8)
      a += th[j] * Kr[j] + th[j+1] * Kr[j+1] + th[j+2] * Kr[j+2] + th[j+3] * Kr[j+3]
         + th[j+4] * Kr[j+4] + th[j+5] * Kr[j+5] + th[j+6] * Kr[j+6] + th[j+7] * Kr[j+7];
    for (; j < m; j++) a += th[j] * Kr[j];
    Av[i] = a;
  }
  __syncthreads();
  double t1l = 0.0, t2l = 0.0;
  for (int i = tid; i < n; i += 256) t2l += (double)(gamma * expf(fminf(Av[i] - 1.f, 30.f)));
  for (int j = tid; j < m; j += 256) t1l += (double)(bc[j] * th[j]);
  double t1 = blockReduceSum(t1l, red);
  double t2 = blockReduceSum(t2l, red);
  if (tid == 0) {
    atomicAdd(&acc[0], t1);
    atomicAdd(&acc[1], t2);
    __threadfence();
    unsigned old = __hip_atomic_fetch_add(&tick[0], 1u, __ATOMIC_ACQ_REL, __HIP_MEMORY_SCOPE_AGENT);
    if (old == 61u) {
      double a0 = __hip_atomic_load(&acc[0], __ATOMIC_RELAXED, __HIP_MEMORY_SCOPE_AGENT);
      double a1 = __hip_atomic_load(&acc[1], __ATOMIC_RELAXED, __HIP_MEMORY_SCOPE_AGENT);
      out[0] = (float)(a0 - a1);
    }
  }
}

// ---------------- launcher ----------------
extern "C" void kernel_launch(void* const* d_in, const int* in_sizes, int n_in,
                              void* d_out, int out_size, void* d_ws, size_t ws_size,
                              hipStream_t stream) {
  const float* sf = (const float*)d_in[0];
  const float* tf = (const float*)d_in[1];
  const int* y = (const int*)d_in[2];
  const int* l = (const int*)d_in[3];
  char* ws = (char*)d_ws;

  double*   acc    = (double*)(ws + WS_ACC);
  unsigned* hist0  = (unsigned*)(ws + WS_HIST0);
  unsigned* histA  = (unsigned*)(ws + WS_HISTA);
  unsigned* histB  = (unsigned*)(ws + WS_HISTB);
  unsigned* h2A    = (unsigned*)(ws + WS_H2A);
  unsigned* h2B    = (unsigned*)(ws + WS_H2B);
  unsigned* state  = (unsigned*)(ws + WS_STATE);
  unsigned* tick   = (unsigned*)(ws + WS_TICK);
  int*      meta   = (int*)(ws + WS_META);
  float*    scal   = (float*)(ws + WS_SCAL);
  int*      perm   = (int*)(ws + WS_PERM);
  float*    xnp    = (float*)(ws + WS_XN);
  float*    Ds     = (float*)(ws + WS_DS);
  float*    gK     = (float*)(ws + WS_KBLK);

  hipMemsetAsync(d_ws, 0, ZERO_BYTES, stream);
  hipLaunchKernelGGL(xn_kernel, dim3(1024), dim3(256), 0, stream, sf, tf, xnp);
  hipLaunchKernelGGL(dist_k, dim3(528), dim3(16, 16), 0, stream, sf, xnp, Ds, hist0);
  hipLaunchKernelGGL(scan0_k, dim3(1), dim3(256), 0, stream, hist0, state);
  hipLaunchKernelGGL(hist1_k, dim3(512), dim3(256), 0, stream, Ds, state, histA, histB);
  hipLaunchKernelGGL(scan1_k, dim3(1), dim3(256), 0, stream, histA, histB, state);
  hipLaunchKernelGGL(hist2_k, dim3(512), dim3(256), 0, stream, Ds, state, h2A, h2B);
  hipLaunchKernelGGL(scan2b_k, dim3(1), dim3(256), 0, stream, h2A, h2B, state, scal, y, l, perm, meta);
  hipLaunchKernelGGL(build_k, dim3(105, 1, NCLASS), dim3(16, 16), 0, stream, sf, tf, xnp, perm, meta, scal, gK);
  hipLaunchKernelGGL(solver_k, dim3(62), dim3(256), 0, stream, gK, meta, scal, acc, tick, (float*)d_out);
}

// Round 14
// 234.627 us; speedup vs baseline: 1.2647x; 1.0081x over previous
//
#include <hip/hip_runtime.h>
#include <math.h>

#define N_TOT   4096
#define N_SRC   2048
#define DIMF    256
#define NCLASS  31
#define LAMBDA  0.01f

// median target ranks among the 2,096,128 strict-lower-triangle values.
#define K_TRI1  1048063LL
#define K_TRI2  1048064LL

// ---- ws layout (bytes) ----
#define WS_ACC    0           // 2 doubles
#define WS_HIST0  64          // 4096 u32
#define WS_HISTA  16448       // 4096 u32
#define WS_HISTB  32832       // 4096 u32
#define WS_H2A    49216       // 256 u32
#define WS_H2B    50240       // 256 u32
#define WS_STATE  51264       // 64 u32 (st[0..7])
#define WS_TICK   51520       // 4 u32 (solver final ticket)
#define WS_META   52288       // 128 i32: ncls[32], m0c[32], cstart[32], blkoff[32]
#define WS_SCAL   52800       // 16 f32: [0]=sigma, [1]=gamma0, [2]=gamma1
#define ZERO_BYTES 53248
#define WS_PERM   53248       // 4096 i32
#define WS_XN     69632       // 4096 f32
#define WS_DS     1048576     // 2048*2048 f32 (lower triangle used)
#define WS_KBLK   17825792    // class K blocks (8 MB budget)

#define MAXW 224
#define MAXM 112
#define WPAD 114   // u16 row stride = 57 dwords (odd -> conflict-free rows & cols)

__device__ __forceinline__ float bf2f(unsigned short h) {
  return __uint_as_float(((unsigned)h) << 16);
}

// ---------------- reductions (256 threads) ----------------
__device__ __forceinline__ double blockReduceSum(double v, double* red) {
#pragma unroll
  for (int o = 32; o > 0; o >>= 1) v += __shfl_down(v, o, 64);
  int w = threadIdx.x >> 6, lane = threadIdx.x & 63;
  __syncthreads();
  if (lane == 0) red[w] = v;
  __syncthreads();
  return red[0] + red[1] + red[2] + red[3];
}

__device__ __forceinline__ void blockReduceSumMax(double s, double mx, double* red,
                                                  double& os, double& om) {
#pragma unroll
  for (int o = 32; o > 0; o >>= 1) {
    s += __shfl_down(s, o, 64);
    double u = __shfl_down(mx, o, 64);
    mx = fmax(mx, u);
  }
  int w = threadIdx.x >> 6, lane = threadIdx.x & 63;
  __syncthreads();
  if (lane == 0) { red[w] = s; red[4 + w] = mx; }
  __syncthreads();
  os = red[0] + red[1] + red[2] + red[3];
  om = fmax(fmax(red[4], red[5]), fmax(red[6], red[7]));
}

// scan over histogram (256 threads)
__device__ void scan_find(const unsigned* hist, int nbins, long long k, unsigned* shOut) {
  __shared__ long long tsum[256];
  int tid = threadIdx.x;
  int per = nbins / 256;
  long long s = 0;
  for (int q = 0; q < per; q++) s += hist[tid * per + q];
  tsum[tid] = s;
  __syncthreads();
  if (tid == 0) {
    long long run = 0;
    for (int t = 0; t < 256; t++) { long long v = tsum[t]; tsum[t] = run; run += v; }
  }
  __syncthreads();
  long long run = tsum[tid];
  for (int q = 0; q < per; q++) {
    unsigned c = hist[tid * per + q];
    if (k >= run && k < run + (long long)c) { shOut[0] = (unsigned)(tid * per + q); shOut[1] = (unsigned)(k - run); }
    run += c;
  }
  __syncthreads();
}

// ---------------- row norms (coalesced, trivial) ----------------
__global__ __launch_bounds__(256) void xn_kernel(const float* __restrict__ sf,
                                                 const float* __restrict__ tf,
                                                 float* __restrict__ xn) {
  int wid = threadIdx.x >> 6, lane = threadIdx.x & 63;
  int row = blockIdx.x * 4 + wid;
  const float* src = (row < N_SRC) ? (sf + (size_t)row * DIMF) : (tf + (size_t)(row - N_SRC) * DIMF);
  float4 v = ((const float4*)src)[lane];
  float s = v.x * v.x + v.y * v.y + v.z * v.z + v.w * v.w;
#pragma unroll
  for (int o = 32; o > 0; o >>= 1) s += __shfl_down(s, o, 64);
  if (lane == 0) xn[row] = s;
}

// ------- source pairwise sq-dists (triangle), pipelined staging, fused hist0 -------
__global__ __launch_bounds__(256) void dist_k(const float* __restrict__ sf,
                                              const float* __restrict__ xn,
                                              float* __restrict__ Ds,
                                              unsigned* __restrict__ h) {
  __shared__ float As[16][68];
  __shared__ float Bs[16][68];
  __shared__ unsigned lh[4096];
  const int tx = threadIdx.x, ty = threadIdx.y;
  const int tid = ty * 16 + tx;
  for (int q = tid; q < 4096; q += 256) lh[q] = 0;
  // triangle block index -> (by,bx), by >= bx
  int b = blockIdx.x;
  int by = (int)((sqrtf(8.f * (float)b + 1.f) - 1.f) * 0.5f);
  while ((by + 1) * (by + 2) / 2 <= b) ++by;
  while (by * (by + 1) / 2 > b) --by;
  int bx = b - by * (by + 1) / 2;
  const int R = by * 64, C = bx * 64;
  const int si = tid >> 2, sq = tid & 3;
  // software-pipelined staging: prefetch kc+16 into regs during compute of kc
  float4 va = ((const float4*)(sf + (size_t)(R + si) * 256 + 0))[sq];
  float4 vb = ((const float4*)(sf + (size_t)(C + si) * 256 + 0))[sq];
  float acc[4][4] = {};
  for (int kc = 0; kc < 256; kc += 16) {
    As[sq * 4 + 0][si] = va.x; As[sq * 4 + 1][si] = va.y; As[sq * 4 + 2][si] = va.z; As[sq * 4 + 3][si] = va.w;
    Bs[sq * 4 + 0][si] = vb.x; Bs[sq * 4 + 1][si] = vb.y; Bs[sq * 4 + 2][si] = vb.z; Bs[sq * 4 + 3][si] = vb.w;
    __syncthreads();
    if (kc + 16 < 256) {
      va = ((const float4*)(sf + (size_t)(R + si) * 256 + kc + 16))[sq];
      vb = ((const float4*)(sf + (size_t)(C + si) * 256 + kc + 16))[sq];
    }
#pragma unroll
    for (int k = 0; k < 16; k++) {
      float4 a = *(const float4*)&As[k][ty * 4];
      float4 b2 = *(const float4*)&Bs[k][tx * 4];
      acc[0][0] += a.x * b2.x; acc[0][1] += a.x * b2.y; acc[0][2] += a.x * b2.z; acc[0][3] += a.x * b2.w;
      acc[1][0] += a.y * b2.x; acc[1][1] += a.y * b2.y; acc[1][2] += a.y * b2.z; acc[1][3] += a.y * b2.w;
      acc[2][0] += a.z * b2.x; acc[2][1] += a.z * b2.y; acc[2][2] += a.z * b2.z; acc[2][3] += a.z * b2.w;
      acc[3][0] += a.w * b2.x; acc[3][1] += a.w * b2.y; acc[3][2] += a.w * b2.z; acc[3][3] += a.w * b2.w;
    }
    __syncthreads();
  }
  int jbase = C + tx * 4;
  float xnj0 = xn[jbase + 0], xnj1 = xn[jbase + 1], xnj2 = xn[jbase + 2], xnj3 = xn[jbase + 3];
#pragma unroll
  for (int r = 0; r < 4; r++) {
    int i = R + ty * 4 + r;
    float xni = xn[i];
    float v[4];
    v[0] = fmaxf(xni + xnj0 - 2.f * acc[r][0], 0.f);
    v[1] = fmaxf(xni + xnj1 - 2.f * acc[r][1], 0.f);
    v[2] = fmaxf(xni + xnj2 - 2.f * acc[r][2], 0.f);
    v[3] = fmaxf(xni + xnj3 - 2.f * acc[r][3], 0.f);
    if (jbase + 3 < i) {
      float4 o; o.x = v[0]; o.y = v[1]; o.z = v[2]; o.w = v[3];
      ((float4*)&Ds[(size_t)i * 2048 + jbase])[0] = o;
      atomicAdd(&lh[__float_as_uint(v[0]) >> 20], 1u);
      atomicAdd(&lh[__float_as_uint(v[1]) >> 20], 1u);
      atomicAdd(&lh[__float_as_uint(v[2]) >> 20], 1u);
      atomicAdd(&lh[__float_as_uint(v[3]) >> 20], 1u);
    } else {
#pragma unroll
      for (int k = 0; k < 4; k++) {
        if (jbase + k < i) {
          Ds[(size_t)i * 2048 + jbase + k] = v[k];
          atomicAdd(&lh[__float_as_uint(v[k]) >> 20], 1u);
        }
      }
    }
  }
  __syncthreads();
  for (int q = tid; q < 4096; q += 256) if (lh[q]) atomicAdd(&h[q], lh[q]);
}

__global__ __launch_bounds__(256) void scan0_k(const unsigned* __restrict__ h, unsigned* __restrict__ st) {
  __shared__ unsigned r0[2];
  __shared__ unsigned r1[2];
  scan_find(h, 4096, K_TRI1, r0);
  scan_find(h, 4096, K_TRI2, r1);
  if (threadIdx.x == 0) { st[0] = r0[0]; st[1] = r0[1]; st[2] = r1[0]; st[3] = r1[1]; }
}

// ---------------- radix pass 1 (triangle reads, sequential rows) ----------------
__global__ __launch_bounds__(256) void hist1_k(const float* __restrict__ Ds, const unsigned* __restrict__ st,
                                               unsigned* __restrict__ hA, unsigned* __restrict__ hB) {
  __shared__ unsigned lA[4096];
  __shared__ unsigned lB[4096];
  for (int i = threadIdx.x; i < 4096; i += 256) { lA[i] = 0; lB[i] = 0; }
  __syncthreads();
  unsigned s0 = st[0], s1 = st[2];
  int gw = (blockIdx.x * 256 + threadIdx.x) >> 6;
  int lane = threadIdx.x & 63;
  const float* row = Ds + (size_t)gw * 2048;
  for (int j = lane; j < gw; j += 64) {
    unsigned u = __float_as_uint(row[j]);
    unsigned hi = u >> 20, mid = (u >> 8) & 0xFFFu;
    if (hi == s0) atomicAdd(&lA[mid], 1u);
    if (hi == s1) atomicAdd(&lB[mid], 1u);
  }
  __syncthreads();
  for (int i = threadIdx.x; i < 4096; i += 256) {
    if (lA[i]) atomicAdd(&hA[i], lA[i]);
    if (lB[i]) atomicAdd(&hB[i], lB[i]);
  }
}

__global__ __launch_bounds__(256) void scan1_k(const unsigned* __restrict__ hA, const unsigned* __restrict__ hB,
                                               unsigned* __restrict__ st) {
  __shared__ unsigned r0[2];
  __shared__ unsigned r1[2];
  long long kA = (long long)st[1];
  long long kB = (long long)st[3];
  scan_find(hA, 4096, kA, r0);
  scan_find(hB, 4096, kB, r1);
  if (threadIdx.x == 0) { st[4] = r0[0]; st[5] = r0[1]; st[6] = r1[0]; st[7] = r1[1]; }
}

// ---------------- radix pass 2 (triangle reads, sequential rows) ----------------
__global__ __launch_bounds__(256) void hist2_k(const float* __restrict__ Ds, const unsigned* __restrict__ st,
                                               unsigned* __restrict__ hA, unsigned* __restrict__ hB) {
  __shared__ unsigned lA[256];
  __shared__ unsigned lB[256];
  lA[threadIdx.x] = 0; lB[threadIdx.x] = 0;
  __syncthreads();
  unsigned p0 = (st[0] << 12) | st[4];
  unsigned p1 = (st[2] << 12) | st[6];
  int gw = (blockIdx.x * 256 + threadIdx.x) >> 6;
  int lane = threadIdx.x & 63;
  const float* row = Ds + (size_t)gw * 2048;
  for (int j = lane; j < gw; j += 64) {
    unsigned u = __float_as_uint(row[j]);
    unsigned pre = u >> 8;
    if (pre == p0) atomicAdd(&lA[u & 0xFFu], 1u);
    if (pre == p1) atomicAdd(&lB[u & 0xFFu], 1u);
  }
  __syncthreads();
  if (lA[threadIdx.x]) atomicAdd(&hA[threadIdx.x], lA[threadIdx.x]);
  if (lB[threadIdx.x]) atomicAdd(&hB[threadIdx.x], lB[threadIdx.x]);
}

// ------- scan2 (sigma) + class/domain bucketing, single block -------
__global__ __launch_bounds__(256) void scan2b_k(const unsigned* __restrict__ hA, const unsigned* __restrict__ hB,
                                                const unsigned* __restrict__ st, float* __restrict__ scal,
                                                const int* __restrict__ y, const int* __restrict__ l,
                                                int* __restrict__ perm, int* __restrict__ meta) {
  int tid = threadIdx.x;
  __shared__ unsigned r0[2];
  __shared__ unsigned r1[2];
  scan_find(hA, 256, (long long)st[5], r0);
  scan_find(hB, 256, (long long)st[7], r1);
  if (tid == 0) {
    unsigned v1 = (st[0] << 20) | (st[4] << 8) | r0[0];
    unsigned v2 = (st[2] << 20) | (st[6] << 8) | r1[0];
    scal[0] = 0.5f * (__uint_as_float(v1) + __uint_as_float(v2));  // sigma
  }
  // ---- class/domain bucketing ----
  __shared__ unsigned cl[64];
  __shared__ unsigned bs2[64];
  __shared__ unsigned cur[64];
  if (tid < 64) cl[tid] = 0;
  __syncthreads();
  for (int i = tid; i < N_TOT; i += 256) atomicAdd(&cl[y[i] * 2 + l[i]], 1u);
  __syncthreads();
  if (tid == 0) {
    unsigned run = 0;
    for (int b2 = 0; b2 < 62; b2++) { bs2[b2] = run; run += cl[b2]; }
    unsigned run2 = 0, cnt0 = 0;
    for (int c = 0; c < NCLASS; c++) {
      int n = (int)(cl[2 * c] + cl[2 * c + 1]);
      meta[c] = n; meta[32 + c] = (int)cl[2 * c]; meta[64 + c] = (int)bs2[2 * c];
      meta[96 + c] = (int)run2; run2 += (unsigned)(n * n);
      cnt0 += cl[2 * c];
    }
    scal[1] = (float)((double)cnt0 / (4096.0 * 4096.0));
    scal[2] = (float)((double)(N_TOT - cnt0) / (4096.0 * 4096.0));
  }
  __syncthreads();
  if (tid < 64) cur[tid] = bs2[tid];
  __syncthreads();
  for (int i = tid; i < N_TOT; i += 256) {
    int b2 = y[i] * 2 + l[i];
    unsigned pos = atomicAdd(&cur[b2], 1u);
    perm[pos] = i;
  }
}

// ------- build per-class K blocks: lower-triangle tiles + mirrored store -------
__global__ __launch_bounds__(256) void build_k(const float* __restrict__ sf, const float* __restrict__ tf,
                                               const float* __restrict__ xn, const int* __restrict__ perm,
                                               const int* __restrict__ meta, const float* __restrict__ scal,
                                               float* __restrict__ gK) {
  const int c = blockIdx.z;
  const int n = meta[c];
  const int cs = meta[64 + c];
  const int bo = meta[96 + c];
  const int T = (n + 15) >> 4;
  int b = blockIdx.x;
  if (b >= T * (T + 1) / 2) return;
  int by = (int)((sqrtf(8.f * (float)b + 1.f) - 1.f) * 0.5f);
  while ((by + 1) * (by + 2) / 2 <= b) ++by;
  while (by * (by + 1) / 2 > b) --by;
  int bx = b - by * (by + 1) / 2;
  const int i0 = by * 16, j0 = bx * 16;
  const int tx = threadIdx.x, ty = threadIdx.y;
  __shared__ float As[16][260];
  __shared__ float Bs[16][260];
  __shared__ float ot[16][17];
  __shared__ int ra[16];
  __shared__ int rb[16];
  int tid = ty * 16 + tx;
  if (tid < 16) { int il = i0 + tid; ra[tid] = (il < n) ? perm[cs + il] : -1; }
  else if (tid < 32) { int jl = j0 + tid - 16; rb[tid - 16] = (jl < n) ? perm[cs + jl] : -1; }
  __syncthreads();
  for (int e = tid; e < 1024; e += 256) {
    int r = e >> 6, q = e & 63;
    int g = ra[r];
    if (g >= 0) {
      const float* src = (g < N_SRC) ? (sf + (size_t)g * DIMF) : (tf + (size_t)(g - N_SRC) * DIMF);
      ((float4*)&As[r][q * 4])[0] = ((const float4*)src)[q];
    }
    int g2 = rb[r];
    if (g2 >= 0) {
      const float* src = (g2 < N_SRC) ? (sf + (size_t)g2 * DIMF) : (tf + (size_t)(g2 - N_SRC) * DIMF);
      ((float4*)&Bs[r][q * 4])[0] = ((const float4*)src)[q];
    }
  }
  __syncthreads();
  int il = i0 + ty, jl = j0 + tx;
  float val = 0.f;
  if (il < n && jl < n) {
    float dot = 0.f;
    const float4* a4 = (const float4*)&As[ty][0];
    const float4* b4 = (const float4*)&Bs[tx][0];
#pragma unroll 16
    for (int q = 0; q < 64; q++) {
      float4 a = a4[q], b2 = b4[q];
      dot += a.x * b2.x + a.y * b2.y + a.z * b2.z + a.w * b2.w;
    }
    int gi = ra[ty], gj = rb[tx];
    float d = xn[gi] + xn[gj] - 2.f * dot;
    val = expf(-d / scal[0]);
    gK[(size_t)bo + (size_t)il * n + jl] = val;
  }
  ot[ty][tx] = val;
  __syncthreads();
  if (by != bx) {
    int il2 = j0 + ty, jl2 = i0 + tx;
    if (il2 < n && jl2 < n) gK[(size_t)bo + (size_t)il2 * n + jl2] = ot[tx][ty];
  }
}

// ---------------- per-(class,domain) Newton-PCG + fused final (256 threads) ----------------
// R14: R12 solver + dual-accumulator ILP in every LDS matvec (halves the
// serial FMA chain per phase -- the binding cost at 1 block/CU).
__global__ __launch_bounds__(256) void solver_k(const float* __restrict__ gK, const int* __restrict__ meta,
                                                const float* __restrict__ scal, double* __restrict__ acc,
                                                unsigned* __restrict__ tick, float* __restrict__ out) {
  const int c = blockIdx.x >> 1, d = blockIdx.x & 1;
  const int n = meta[c];
  const int m0 = meta[32 + c];
  const int m = d ? (n - m0) : m0;
  const int c0 = d ? m0 : 0;
  const int bo = meta[96 + c];
  const float gamma = scal[1 + d];
  const int tid = threadIdx.x;
  const int wv = tid >> 6, lane = tid & 63;

  __shared__ unsigned short Wl[MAXW * WPAD];   // 51072 B
  __shared__ float pS[4 * MAXM];
  __shared__ float pD[4 * MAXM];
  __shared__ float Av[MAXW];
  __shared__ float Sv[MAXW];
  __shared__ float Uv[MAXW];
  __shared__ float Bq[MAXW];
  __shared__ float bc[MAXM];
  __shared__ float th[MAXM + 3];
  __shared__ float gv[MAXM];
  __shared__ float dgv[MAXM];
  __shared__ float pv[MAXM + 3];
  __shared__ float rv[MAXM + 1];
  __shared__ float zv[MAXM + 1];
  __shared__ float xv[MAXM + 3];
  __shared__ double red[16];

  const float* K = gK + bo;
  const int st = n;
  const int mp2 = (m + 1) & ~1;
  const int iw0 = (n * wv) >> 2, iw1 = (n * (wv + 1)) >> 2;

  for (int i = tid >> 2; i < n; i += 64) {
    const float* Kr = K + (size_t)i * st + c0;
    unsigned short* Wr = Wl + i * WPAD;
    for (int j = (tid & 3); j < m; j += 4) {
      unsigned u = __float_as_uint(Kr[j]);
      u += 0x7fffu + ((u >> 16) & 1u);   // RNE to bf16
      Wr[j] = (unsigned short)(u >> 16);
    }
    if ((tid & 3) == 0 && (m & 1)) Wr[m] = 0;
  }
  {
    const int r0 = (m * wv) >> 2, r1 = (m * (wv + 1)) >> 2;
    for (int j = lane; j < m; j += 64) {
      const float* Kr = K + (size_t)(c0 + j) * st + c0;
      float s = 0.f;
      for (int r = r0; r < r1; r++) s += Kr[r];
      pS[wv * MAXM + j] = s;
    }
  }
  __syncthreads();
  for (int j = tid; j < mp2 + 2; j += 256) {
    if (j < m) bc[j] = (pS[j] + pS[MAXM + j] + pS[2 * MAXM + j] + pS[3 * MAXM + j]) * (1.0f / 4096.0f);
    th[j] = 0.f;   // includes pad slots [m..mp2+1]
  }
  __syncthreads();

  // dual-chain LDS row matvec: y = W(row i) . vec  (vec padded to mp2+2)
#define ROWMV(Wr, vec, OUT)                                              \
  {                                                                      \
    float a0_ = 0.f, a1_ = 0.f;                                          \
    int j_ = 0;                                                          \
    for (; j_ + 3 < mp2; j_ += 4) {                                      \
      unsigned u0_ = *(const unsigned*)((Wr) + j_);                      \
      unsigned u1_ = *(const unsigned*)((Wr) + j_ + 2);                  \
      a0_ += __uint_as_float(u0_ << 16) * (vec)[j_]                      \
           + __uint_as_float(u0_ & 0xffff0000u) * (vec)[j_ + 1];         \
      a1_ += __uint_as_float(u1_ << 16) * (vec)[j_ + 2]                  \
           + __uint_as_float(u1_ & 0xffff0000u) * (vec)[j_ + 3];         \
    }                                                                    \
    for (; j_ < mp2; j_ += 2) {                                          \
      unsigned u0_ = *(const unsigned*)((Wr) + j_);                      \
      a0_ += __uint_as_float(u0_ << 16) * (vec)[j_]                      \
           + __uint_as_float(u0_ & 0xffff0000u) * (vec)[j_ + 1];         \
    }                                                                    \
    OUT = a0_ + a1_;                                                     \
  }

  for (int it = 0; it < 25; it++) {
    double o = 0.0;
    if (it == 0) {
      const float s0c = gamma * expf(-1.f);
      for (int i = tid; i < n; i += 256) { Av[i] = 0.f; Sv[i] = s0c; o += (double)s0c; }
    } else {
      // merged: Av matvec -> S -> obj contribution (no barrier inside)
      for (int i = tid; i < n; i += 256) {
        const unsigned short* Wr = Wl + i * WPAD;
        float a;
        ROWMV(Wr, th, a);
        Av[i] = a;
        float si = gamma * expf(fminf(a - 1.f, 30.f));
        Sv[i] = si; o += (double)si;
      }
      for (int j = tid; j < m; j += 256) {
        float t_ = th[j];
        o += (double)(-bc[j] * t_ + LAMBDA * t_ * t_);
      }
    }
    __syncthreads();
    // ---- gradient (+ Jacobi diag at it==0 only; frozen after), dual chains ----
    if (it == 0) {
      for (int j = lane; j < m; j += 64) {
        const unsigned short* Wc = Wl + j;
        float s0_ = 0.f, s1_ = 0.f, d0_ = 0.f, d1_ = 0.f;
        int i = iw0;
        for (; i + 7 < iw1; i += 8) {
          float w0 = bf2f(Wc[(i + 0) * WPAD]), w1 = bf2f(Wc[(i + 1) * WPAD]);
          float w2 = bf2f(Wc[(i + 2) * WPAD]), w3 = bf2f(Wc[(i + 3) * WPAD]);
          float w4 = bf2f(Wc[(i + 4) * WPAD]), w5 = bf2f(Wc[(i + 5) * WPAD]);
          float w6 = bf2f(Wc[(i + 6) * WPAD]), w7 = bf2f(Wc[(i + 7) * WPAD]);
          float a0 = w0 * Sv[i], a1 = w1 * Sv[i + 1], a2 = w2 * Sv[i + 2], a3 = w3 * Sv[i + 3];
          float a4 = w4 * Sv[i + 4], a5 = w5 * Sv[i + 5], a6 = w6 * Sv[i + 6], a7 = w7 * Sv[i + 7];
          s0_ += a0 + a1 + a2 + a3;
          s1_ += a4 + a5 + a6 + a7;
          d0_ += a0 * w0 + a1 * w1 + a2 * w2 + a3 * w3;
          d1_ += a4 * w4 + a5 * w5 + a6 * w6 + a7 * w7;
        }
        for (; i < iw1; i++) { float w = bf2f(Wc[i * WPAD]); float a = w * Sv[i]; s0_ += a; d0_ += a * w; }
        pS[wv * MAXM + j] = s0_ + s1_; pD[wv * MAXM + j] = d0_ + d1_;
      }
    } else {
      for (int j = lane; j < m; j += 64) {
        const unsigned short* Wc = Wl + j;
        float s0_ = 0.f, s1_ = 0.f;
        int i = iw0;
        for (; i + 7 < iw1; i += 8) {
          s0_ += bf2f(Wc[(i+0)*WPAD]) * Sv[i]   + bf2f(Wc[(i+1)*WPAD]) * Sv[i+1]
               + bf2f(Wc[(i+2)*WPAD]) * Sv[i+2] + bf2f(Wc[(i+3)*WPAD]) * Sv[i+3];
          s1_ += bf2f(Wc[(i+4)*WPAD]) * Sv[i+4] + bf2f(Wc[(i+5)*WPAD]) * Sv[i+5]
               + bf2f(Wc[(i+6)*WPAD]) * Sv[i+6] + bf2f(Wc[(i+7)*WPAD]) * Sv[i+7];
        }
        for (; i < iw1; i++) s0_ += bf2f(Wc[i * WPAD]) * Sv[i];
        pS[wv * MAXM + j] = s0_ + s1_;
      }
    }
    __syncthreads();
    double gm = 0.0;
    for (int j = tid; j < m; j += 256) {
      float s_ = pS[j] + pS[MAXM + j] + pS[2 * MAXM + j] + pS[3 * MAXM + j];
      if (it == 0) {
        float ds_ = pD[j] + pD[MAXM + j] + pD[2 * MAXM + j] + pD[3 * MAXM + j];
        dgv[j] = ds_ + 2.f * LAMBDA;
      }
      float g = s_ - bc[j] + 2.f * LAMBDA * th[j];
      gv[j] = g;
      double ag = fabs((double)g); if (ag > gm) gm = ag;
    }
    double obj, gmax;
    blockReduceSumMax(o, gm, red, obj, gmax);
    if (gmax < 1e-5) break;

    // ---- PCG solve H x = -g (frozen Jacobi precond), inexact-Newton tol ----
    const double tolf = (it == 0) ? 1e-2 : ((it == 1) ? 1e-3 : 1e-4);
    double rz = 0.0;
    for (int j = tid; j < mp2 + 2; j += 256) {
      float r0 = (j < m) ? -gv[j] : 0.f;
      float z0 = (j < m) ? r0 / dgv[j] : 0.f;
      if (j < mp2) { rv[j] = r0; zv[j] = z0; }
      pv[j] = (j < mp2) ? z0 : 0.f;
      xv[j] = 0.f;
      rz += (double)r0 * (double)z0;
    }
    rz = blockReduceSum(rz, red);
    double rz0 = rz;
    double gtpacc = 0.0;   // block-uniform: sum of alpha_k * rz_k = -g^T x
    for (int cg = 0; cg < 12; cg++) {
      __syncthreads();
      for (int i = tid; i < n; i += 256) {
        const unsigned short* Wr = Wl + i * WPAD;
        float a;
        ROWMV(Wr, pv, a);
        Uv[i] = a * Sv[i];
      }
      __syncthreads();
      for (int j = lane; j < m; j += 64) {
        const unsigned short* Wc = Wl + j;
        float q0 = 0.f, q1 = 0.f;
        int i = iw0;
        for (; i + 7 < iw1; i += 8) {
          q0 += bf2f(Wc[(i+0)*WPAD]) * Uv[i]   + bf2f(Wc[(i+1)*WPAD]) * Uv[i+1]
              + bf2f(Wc[(i+2)*WPAD]) * Uv[i+2] + bf2f(Wc[(i+3)*WPAD]) * Uv[i+3];
          q1 += bf2f(Wc[(i+4)*WPAD]) * Uv[i+4] + bf2f(Wc[(i+5)*WPAD]) * Uv[i+5]
              + bf2f(Wc[(i+6)*WPAD]) * Uv[i+6] + bf2f(Wc[(i+7)*WPAD]) * Uv[i+7];
        }
        for (; i < iw1; i++) q0 += bf2f(Wc[i * WPAD]) * Uv[i];
        pS[wv * MAXM + j] = q0 + q1;
      }
      __syncthreads();
      double pq = 0.0;
      for (int j = tid; j < m; j += 256) {
        float q = pS[j] + pS[MAXM + j] + pS[2 * MAXM + j] + pS[3 * MAXM + j] + 2.f * LAMBDA * pv[j];
        Bq[j] = q;
        pq += (double)pv[j] * (double)q;
      }
      pq = blockReduceSum(pq, red);
      if (!(pq > 0.0)) break;
      float alpha = (float)(rz / pq);
      gtpacc += (double)alpha * rz;
      double rznew = 0.0;
      for (int j = tid; j < m; j += 256) {
        xv[j] += alpha * pv[j];
        float rn = rv[j] - alpha * Bq[j];
        rv[j] = rn;
        float zn = rn / dgv[j];
        zv[j] = zn;
        rznew += (double)rn * (double)zn;
      }
      rznew = blockReduceSum(rznew, red);
      if (rznew < tolf * rz0 || cg == 11) break;
      float beta = (float)(rznew / rz);
      for (int j = tid; j < m; j += 256) pv[j] = zv[j] + beta * pv[j];
      rz = rznew;
    }
    __syncthreads();
    // gtp = g^T x = -gtpacc (exact CG identity); no reduction phase needed
    double gtp = -gtpacc;
    if (!(gtp < 0.0)) break;   // no CG progress => converged/degenerate

    float t = 1.f;
    if (-gtp >= 1e-4) {
      for (int i = tid; i < n; i += 256) {
        const unsigned short* Wr = Wl + i * WPAD;
        float a;
        ROWMV(Wr, xv, a);
        Bq[i] = a;
      }
      __syncthreads();
      for (int ls = 0; ls < 10; ls++) {
        double ol = 0.0;
        for (int i = tid; i < n; i += 256)
          ol += (double)(gamma * expf(fminf(Av[i] + t * Bq[i] - 1.f, 30.f)));
        for (int j = tid; j < m; j += 256) {
          float tj = th[j] + t * xv[j];
          ol += (double)(-bc[j] * tj + LAMBDA * tj * tj);
        }
        double ot2 = blockReduceSum(ol, red);
        if (ot2 <= obj + 1e-4 * (double)t * gtp) break;
        t *= 0.5f;
      }
    }
    for (int j = tid; j < mp2; j += 256) th[j] += t * xv[j];
    __syncthreads();
  }

  // ---- final exact f32 evaluation (global K, f32 theta), dual chains ----
  __syncthreads();
  for (int i = tid; i < n; i += 256) {
    const float* Kr = K + (size_t)i * st + c0;
    float a0 = 0.f, a1 = 0.f;
    int j = 0;
    for (; j + 7 < m; j += 8) {
      a0 += th[j] * Kr[j] + th[j+1] * Kr[j+1] + th[j+2] * Kr[j+2] + th[j+3] * Kr[j+3];
      a1 += th[j+4] * Kr[j+4] + th[j+5] * Kr[j+5] + th[j+6] * Kr[j+6] + th[j+7] * Kr[j+7];
    }
    for (; j < m; j++) a0 += th[j] * Kr[j];
    Av[i] = a0 + a1;
  }
  __syncthreads();
  double t1l = 0.0, t2l = 0.0;
  for (int i = tid; i < n; i += 256) t2l += (double)(gamma * expf(fminf(Av[i] - 1.f, 30.f)));
  for (int j = tid; j < m; j += 256) t1l += (double)(bc[j] * th[j]);
  double t1 = blockReduceSum(t1l, red);
  double t2 = blockReduceSum(t2l, red);
  if (tid == 0) {
    atomicAdd(&acc[0], t1);
    atomicAdd(&acc[1], t2);
    __threadfence();
    unsigned old = __hip_atomic_fetch_add(&tick[0], 1u, __ATOMIC_ACQ_REL, __HIP_MEMORY_SCOPE_AGENT);
    if (old == 61u) {
      double a0 = __hip_atomic_load(&acc[0], __ATOMIC_RELAXED, __HIP_MEMORY_SCOPE_AGENT);
      double a1 = __hip_atomic_load(&acc[1], __ATOMIC_RELAXED, __HIP_MEMORY_SCOPE_AGENT);
      out[0] = (float)(a0 - a1);
    }
  }
#undef ROWMV
}

// ---------------- launcher ----------------
extern "C" void kernel_launch(void* const* d_in, const int* in_sizes, int n_in,
                              void* d_out, int out_size, void* d_ws, size_t ws_size,
                              hipStream_t stream) {
  const float* sf = (const float*)d_in[0];
  const float* tf = (const float*)d_in[1];
  const int* y = (const int*)d_in[2];
  const int* l = (const int*)d_in[3];
  char* ws = (char*)d_ws;

  double*   acc    = (double*)(ws + WS_ACC);
  unsigned* hist0  = (unsigned*)(ws + WS_HIST0);
  unsigned* histA  = (unsigned*)(ws + WS_HISTA);
  unsigned* histB  = (unsigned*)(ws + WS_HISTB);
  unsigned* h2A    = (unsigned*)(ws + WS_H2A);
  unsigned* h2B    = (unsigned*)(ws + WS_H2B);
  unsigned* state  = (unsigned*)(ws + WS_STATE);
  unsigned* tick   = (unsigned*)(ws + WS_TICK);
  int*      meta   = (int*)(ws + WS_META);
  float*    scal   = (float*)(ws + WS_SCAL);
  int*      perm   = (int*)(ws + WS_PERM);
  float*    xnp    = (float*)(ws + WS_XN);
  float*    Ds     = (float*)(ws + WS_DS);
  float*    gK     = (float*)(ws + WS_KBLK);

  hipMemsetAsync(d_ws, 0, ZERO_BYTES, stream);
  hipLaunchKernelGGL(xn_kernel, dim3(1024), dim3(256), 0, stream, sf, tf, xnp);
  hipLaunchKernelGGL(dist_k, dim3(528), dim3(16, 16), 0, stream, sf, xnp, Ds, hist0);
  hipLaunchKernelGGL(scan0_k, dim3(1), dim3(256), 0, stream, hist0, state);
  hipLaunchKernelGGL(hist1_k, dim3(512), dim3(256), 0, stream, Ds, state, histA, histB);
  hipLaunchKernelGGL(scan1_k, dim3(1), dim3(256), 0, stream, histA, histB, state);
  hipLaunchKernelGGL(hist2_k, dim3(512), dim3(256), 0, stream, Ds, state, h2A, h2B);
  hipLaunchKernelGGL(scan2b_k, dim3(1), dim3(256), 0, stream, h2A, h2B, state, scal, y, l, perm, meta);
  hipLaunchKernelGGL(build_k, dim3(105, 1, NCLASS), dim3(16, 16), 0, stream, sf, tf, xnp, perm, meta, scal, gK);
  hipLaunchKernelGGL(solver_k, dim3(62), dim3(256), 0, stream, gK, meta, scal, acc, tick, (float*)d_out);
}

// Round 15
// 231.666 us; speedup vs baseline: 1.2809x; 1.0128x over previous
//
#include <hip/hip_runtime.h>
#include <math.h>

#define N_TOT   4096
#define N_SRC   2048
#define DIMF    256
#define NCLASS  31
#define LAMBDA  0.01f

// median target ranks among the 2,096,128 strict-lower-triangle values.
#define K_TRI1  1048063LL
#define K_TRI2  1048064LL

// ---- ws layout (bytes) ----
#define WS_ACC    0           // 2 doubles
#define WS_HIST0  64          // 4096 u32
#define WS_HISTA  16448       // 4096 u32
#define WS_HISTB  32832       // 4096 u32
#define WS_H2A    49216       // 256 u32
#define WS_H2B    50240       // 256 u32
#define WS_STATE  51264       // 64 u32 (st[0..7])
#define WS_TICK   51520       // 4 u32 (solver final ticket)
#define WS_META   52288       // 128 i32: ncls[32], m0c[32], cstart[32], blkoff[32]
#define WS_SCAL   52800       // 16 f32: [0]=sigma, [1]=gamma0, [2]=gamma1
#define ZERO_BYTES 53248
#define WS_PERM   53248       // 4096 i32
#define WS_XN     69632       // 4096 f32
#define WS_DS     1048576     // 2048*2048 f32 (lower triangle used)
#define WS_KBLK   17825792    // class K blocks (8 MB budget)

#define MAXW 224
#define MAXM 112
#define WPAD 114   // u16 row stride = 57 dwords (odd -> conflict-free rows & cols)

__device__ __forceinline__ float bf2f(unsigned short h) {
  return __uint_as_float(((unsigned)h) << 16);
}

// ---------------- reductions (256 threads) ----------------
__device__ __forceinline__ double blockReduceSum(double v, double* red) {
#pragma unroll
  for (int o = 32; o > 0; o >>= 1) v += __shfl_down(v, o, 64);
  int w = threadIdx.x >> 6, lane = threadIdx.x & 63;
  __syncthreads();
  if (lane == 0) red[w] = v;
  __syncthreads();
  return red[0] + red[1] + red[2] + red[3];
}

__device__ __forceinline__ void blockReduceSumMax(double s, double mx, double* red,
                                                  double& os, double& om) {
#pragma unroll
  for (int o = 32; o > 0; o >>= 1) {
    s += __shfl_down(s, o, 64);
    double u = __shfl_down(mx, o, 64);
    mx = fmax(mx, u);
  }
  int w = threadIdx.x >> 6, lane = threadIdx.x & 63;
  __syncthreads();
  if (lane == 0) { red[w] = s; red[4 + w] = mx; }
  __syncthreads();
  os = red[0] + red[1] + red[2] + red[3];
  om = fmax(fmax(red[4], red[5]), fmax(red[6], red[7]));
}

// scan over histogram (256 threads)
__device__ void scan_find(const unsigned* hist, int nbins, long long k, unsigned* shOut) {
  __shared__ long long tsum[256];
  int tid = threadIdx.x;
  int per = nbins / 256;
  long long s = 0;
  for (int q = 0; q < per; q++) s += hist[tid * per + q];
  tsum[tid] = s;
  __syncthreads();
  if (tid == 0) {
    long long run = 0;
    for (int t = 0; t < 256; t++) { long long v = tsum[t]; tsum[t] = run; run += v; }
  }
  __syncthreads();
  long long run = tsum[tid];
  for (int q = 0; q < per; q++) {
    unsigned c = hist[tid * per + q];
    if (k >= run && k < run + (long long)c) { shOut[0] = (unsigned)(tid * per + q); shOut[1] = (unsigned)(k - run); }
    run += c;
  }
  __syncthreads();
}

// ---------------- row norms (coalesced, trivial) ----------------
__global__ __launch_bounds__(256) void xn_kernel(const float* __restrict__ sf,
                                                 const float* __restrict__ tf,
                                                 float* __restrict__ xn) {
  int wid = threadIdx.x >> 6, lane = threadIdx.x & 63;
  int row = blockIdx.x * 4 + wid;
  const float* src = (row < N_SRC) ? (sf + (size_t)row * DIMF) : (tf + (size_t)(row - N_SRC) * DIMF);
  float4 v = ((const float4*)src)[lane];
  float s = v.x * v.x + v.y * v.y + v.z * v.z + v.w * v.w;
#pragma unroll
  for (int o = 32; o > 0; o >>= 1) s += __shfl_down(s, o, 64);
  if (lane == 0) xn[row] = s;
}

// ------- source pairwise sq-dists (triangle), pipelined staging, fused hist0 -------
__global__ __launch_bounds__(256) void dist_k(const float* __restrict__ sf,
                                              const float* __restrict__ xn,
                                              float* __restrict__ Ds,
                                              unsigned* __restrict__ h) {
  __shared__ float As[16][68];
  __shared__ float Bs[16][68];
  __shared__ unsigned lh[4096];
  const int tx = threadIdx.x, ty = threadIdx.y;
  const int tid = ty * 16 + tx;
  for (int q = tid; q < 4096; q += 256) lh[q] = 0;
  // triangle block index -> (by,bx), by >= bx
  int b = blockIdx.x;
  int by = (int)((sqrtf(8.f * (float)b + 1.f) - 1.f) * 0.5f);
  while ((by + 1) * (by + 2) / 2 <= b) ++by;
  while (by * (by + 1) / 2 > b) --by;
  int bx = b - by * (by + 1) / 2;
  const int R = by * 64, C = bx * 64;
  const int si = tid >> 2, sq = tid & 3;
  // software-pipelined staging: prefetch kc+16 into regs during compute of kc
  float4 va = ((const float4*)(sf + (size_t)(R + si) * 256 + 0))[sq];
  float4 vb = ((const float4*)(sf + (size_t)(C + si) * 256 + 0))[sq];
  float acc[4][4] = {};
  for (int kc = 0; kc < 256; kc += 16) {
    As[sq * 4 + 0][si] = va.x; As[sq * 4 + 1][si] = va.y; As[sq * 4 + 2][si] = va.z; As[sq * 4 + 3][si] = va.w;
    Bs[sq * 4 + 0][si] = vb.x; Bs[sq * 4 + 1][si] = vb.y; Bs[sq * 4 + 2][si] = vb.z; Bs[sq * 4 + 3][si] = vb.w;
    __syncthreads();
    if (kc + 16 < 256) {
      va = ((const float4*)(sf + (size_t)(R + si) * 256 + kc + 16))[sq];
      vb = ((const float4*)(sf + (size_t)(C + si) * 256 + kc + 16))[sq];
    }
#pragma unroll
    for (int k = 0; k < 16; k++) {
      float4 a = *(const float4*)&As[k][ty * 4];
      float4 b2 = *(const float4*)&Bs[k][tx * 4];
      acc[0][0] += a.x * b2.x; acc[0][1] += a.x * b2.y; acc[0][2] += a.x * b2.z; acc[0][3] += a.x * b2.w;
      acc[1][0] += a.y * b2.x; acc[1][1] += a.y * b2.y; acc[1][2] += a.y * b2.z; acc[1][3] += a.y * b2.w;
      acc[2][0] += a.z * b2.x; acc[2][1] += a.z * b2.y; acc[2][2] += a.z * b2.z; acc[2][3] += a.z * b2.w;
      acc[3][0] += a.w * b2.x; acc[3][1] += a.w * b2.y; acc[3][2] += a.w * b2.z; acc[3][3] += a.w * b2.w;
    }
    __syncthreads();
  }
  int jbase = C + tx * 4;
  float xnj0 = xn[jbase + 0], xnj1 = xn[jbase + 1], xnj2 = xn[jbase + 2], xnj3 = xn[jbase + 3];
#pragma unroll
  for (int r = 0; r < 4; r++) {
    int i = R + ty * 4 + r;
    float xni = xn[i];
    float v[4];
    v[0] = fmaxf(xni + xnj0 - 2.f * acc[r][0], 0.f);
    v[1] = fmaxf(xni + xnj1 - 2.f * acc[r][1], 0.f);
    v[2] = fmaxf(xni + xnj2 - 2.f * acc[r][2], 0.f);
    v[3] = fmaxf(xni + xnj3 - 2.f * acc[r][3], 0.f);
    if (jbase + 3 < i) {
      float4 o; o.x = v[0]; o.y = v[1]; o.z = v[2]; o.w = v[3];
      ((float4*)&Ds[(size_t)i * 2048 + jbase])[0] = o;
      atomicAdd(&lh[__float_as_uint(v[0]) >> 20], 1u);
      atomicAdd(&lh[__float_as_uint(v[1]) >> 20], 1u);
      atomicAdd(&lh[__float_as_uint(v[2]) >> 20], 1u);
      atomicAdd(&lh[__float_as_uint(v[3]) >> 20], 1u);
    } else {
#pragma unroll
      for (int k = 0; k < 4; k++) {
        if (jbase + k < i) {
          Ds[(size_t)i * 2048 + jbase + k] = v[k];
          atomicAdd(&lh[__float_as_uint(v[k]) >> 20], 1u);
        }
      }
    }
  }
  __syncthreads();
  for (int q = tid; q < 4096; q += 256) if (lh[q]) atomicAdd(&h[q], lh[q]);
}

__global__ __launch_bounds__(256) void scan0_k(const unsigned* __restrict__ h, unsigned* __restrict__ st) {
  __shared__ unsigned r0[2];
  __shared__ unsigned r1[2];
  scan_find(h, 4096, K_TRI1, r0);
  scan_find(h, 4096, K_TRI2, r1);
  if (threadIdx.x == 0) { st[0] = r0[0]; st[1] = r0[1]; st[2] = r1[0]; st[3] = r1[1]; }
}

// ---------------- radix pass 1 (triangle reads, sequential rows) ----------------
__global__ __launch_bounds__(256) void hist1_k(const float* __restrict__ Ds, const unsigned* __restrict__ st,
                                               unsigned* __restrict__ hA, unsigned* __restrict__ hB) {
  __shared__ unsigned lA[4096];
  __shared__ unsigned lB[4096];
  for (int i = threadIdx.x; i < 4096; i += 256) { lA[i] = 0; lB[i] = 0; }
  __syncthreads();
  unsigned s0 = st[0], s1 = st[2];
  int gw = (blockIdx.x * 256 + threadIdx.x) >> 6;
  int lane = threadIdx.x & 63;
  const float* row = Ds + (size_t)gw * 2048;
  for (int j = lane; j < gw; j += 64) {
    unsigned u = __float_as_uint(row[j]);
    unsigned hi = u >> 20, mid = (u >> 8) & 0xFFFu;
    if (hi == s0) atomicAdd(&lA[mid], 1u);
    if (hi == s1) atomicAdd(&lB[mid], 1u);
  }
  __syncthreads();
  for (int i = threadIdx.x; i < 4096; i += 256) {
    if (lA[i]) atomicAdd(&hA[i], lA[i]);
    if (lB[i]) atomicAdd(&hB[i], lB[i]);
  }
}

__global__ __launch_bounds__(256) void scan1_k(const unsigned* __restrict__ hA, const unsigned* __restrict__ hB,
                                               unsigned* __restrict__ st) {
  __shared__ unsigned r0[2];
  __shared__ unsigned r1[2];
  long long kA = (long long)st[1];
  long long kB = (long long)st[3];
  scan_find(hA, 4096, kA, r0);
  scan_find(hB, 4096, kB, r1);
  if (threadIdx.x == 0) { st[4] = r0[0]; st[5] = r0[1]; st[6] = r1[0]; st[7] = r1[1]; }
}

// ---------------- radix pass 2 (triangle reads, sequential rows) ----------------
__global__ __launch_bounds__(256) void hist2_k(const float* __restrict__ Ds, const unsigned* __restrict__ st,
                                               unsigned* __restrict__ hA, unsigned* __restrict__ hB) {
  __shared__ unsigned lA[256];
  __shared__ unsigned lB[256];
  lA[threadIdx.x] = 0; lB[threadIdx.x] = 0;
  __syncthreads();
  unsigned p0 = (st[0] << 12) | st[4];
  unsigned p1 = (st[2] << 12) | st[6];
  int gw = (blockIdx.x * 256 + threadIdx.x) >> 6;
  int lane = threadIdx.x & 63;
  const float* row = Ds + (size_t)gw * 2048;
  for (int j = lane; j < gw; j += 64) {
    unsigned u = __float_as_uint(row[j]);
    unsigned pre = u >> 8;
    if (pre == p0) atomicAdd(&lA[u & 0xFFu], 1u);
    if (pre == p1) atomicAdd(&lB[u & 0xFFu], 1u);
  }
  __syncthreads();
  if (lA[threadIdx.x]) atomicAdd(&hA[threadIdx.x], lA[threadIdx.x]);
  if (lB[threadIdx.x]) atomicAdd(&hB[threadIdx.x], lB[threadIdx.x]);
}

// ------- scan2 (sigma) + class/domain bucketing, single block -------
__global__ __launch_bounds__(256) void scan2b_k(const unsigned* __restrict__ hA, const unsigned* __restrict__ hB,
                                                const unsigned* __restrict__ st, float* __restrict__ scal,
                                                const int* __restrict__ y, const int* __restrict__ l,
                                                int* __restrict__ perm, int* __restrict__ meta) {
  int tid = threadIdx.x;
  __shared__ unsigned r0[2];
  __shared__ unsigned r1[2];
  scan_find(hA, 256, (long long)st[5], r0);
  scan_find(hB, 256, (long long)st[7], r1);
  if (tid == 0) {
    unsigned v1 = (st[0] << 20) | (st[4] << 8) | r0[0];
    unsigned v2 = (st[2] << 20) | (st[6] << 8) | r1[0];
    scal[0] = 0.5f * (__uint_as_float(v1) + __uint_as_float(v2));  // sigma
  }
  // ---- class/domain bucketing ----
  __shared__ unsigned cl[64];
  __shared__ unsigned bs2[64];
  __shared__ unsigned cur[64];
  if (tid < 64) cl[tid] = 0;
  __syncthreads();
  for (int i = tid; i < N_TOT; i += 256) atomicAdd(&cl[y[i] * 2 + l[i]], 1u);
  __syncthreads();
  if (tid == 0) {
    unsigned run = 0;
    for (int b2 = 0; b2 < 62; b2++) { bs2[b2] = run; run += cl[b2]; }
    unsigned run2 = 0, cnt0 = 0;
    for (int c = 0; c < NCLASS; c++) {
      int n = (int)(cl[2 * c] + cl[2 * c + 1]);
      meta[c] = n; meta[32 + c] = (int)cl[2 * c]; meta[64 + c] = (int)bs2[2 * c];
      meta[96 + c] = (int)run2; run2 += (unsigned)(n * n);
      cnt0 += cl[2 * c];
    }
    scal[1] = (float)((double)cnt0 / (4096.0 * 4096.0));
    scal[2] = (float)((double)(N_TOT - cnt0) / (4096.0 * 4096.0));
  }
  __syncthreads();
  if (tid < 64) cur[tid] = bs2[tid];
  __syncthreads();
  for (int i = tid; i < N_TOT; i += 256) {
    int b2 = y[i] * 2 + l[i];
    unsigned pos = atomicAdd(&cur[b2], 1u);
    perm[pos] = i;
  }
}

// ------- build per-class K blocks: lower-triangle tiles + mirrored store -------
__global__ __launch_bounds__(256) void build_k(const float* __restrict__ sf, const float* __restrict__ tf,
                                               const float* __restrict__ xn, const int* __restrict__ perm,
                                               const int* __restrict__ meta, const float* __restrict__ scal,
                                               float* __restrict__ gK) {
  const int c = blockIdx.z;
  const int n = meta[c];
  const int cs = meta[64 + c];
  const int bo = meta[96 + c];
  const int T = (n + 15) >> 4;
  int b = blockIdx.x;
  if (b >= T * (T + 1) / 2) return;
  int by = (int)((sqrtf(8.f * (float)b + 1.f) - 1.f) * 0.5f);
  while ((by + 1) * (by + 2) / 2 <= b) ++by;
  while (by * (by + 1) / 2 > b) --by;
  int bx = b - by * (by + 1) / 2;
  const int i0 = by * 16, j0 = bx * 16;
  const int tx = threadIdx.x, ty = threadIdx.y;
  __shared__ float As[16][260];
  __shared__ float Bs[16][260];
  __shared__ float ot[16][17];
  __shared__ int ra[16];
  __shared__ int rb[16];
  int tid = ty * 16 + tx;
  if (tid < 16) { int il = i0 + tid; ra[tid] = (il < n) ? perm[cs + il] : -1; }
  else if (tid < 32) { int jl = j0 + tid - 16; rb[tid - 16] = (jl < n) ? perm[cs + jl] : -1; }
  __syncthreads();
  for (int e = tid; e < 1024; e += 256) {
    int r = e >> 6, q = e & 63;
    int g = ra[r];
    if (g >= 0) {
      const float* src = (g < N_SRC) ? (sf + (size_t)g * DIMF) : (tf + (size_t)(g - N_SRC) * DIMF);
      ((float4*)&As[r][q * 4])[0] = ((const float4*)src)[q];
    }
    int g2 = rb[r];
    if (g2 >= 0) {
      const float* src = (g2 < N_SRC) ? (sf + (size_t)g2 * DIMF) : (tf + (size_t)(g2 - N_SRC) * DIMF);
      ((float4*)&Bs[r][q * 4])[0] = ((const float4*)src)[q];
    }
  }
  __syncthreads();
  int il = i0 + ty, jl = j0 + tx;
  float val = 0.f;
  if (il < n && jl < n) {
    float dot = 0.f;
    const float4* a4 = (const float4*)&As[ty][0];
    const float4* b4 = (const float4*)&Bs[tx][0];
#pragma unroll 16
    for (int q = 0; q < 64; q++) {
      float4 a = a4[q], b2 = b4[q];
      dot += a.x * b2.x + a.y * b2.y + a.z * b2.z + a.w * b2.w;
    }
    int gi = ra[ty], gj = rb[tx];
    float d = xn[gi] + xn[gj] - 2.f * dot;
    val = expf(-d / scal[0]);
    gK[(size_t)bo + (size_t)il * n + jl] = val;
  }
  ot[ty][tx] = val;
  __syncthreads();
  if (by != bx) {
    int il2 = j0 + ty, jl2 = i0 + tx;
    if (il2 < n && jl2 < n) gK[(size_t)bo + (size_t)il2 * n + jl2] = ot[tx][ty];
  }
}

// ---------------- per-(class,domain) Newton-PCG + fused final (256 threads) ----------------
// R12-proven solver (best measured 60.8): merged Av+S+obj phase, gtp via CG
// identity, frozen Jacobi, it=0 shortcut, inexact CG tol, compiler unroll-4.
__global__ __launch_bounds__(256) void solver_k(const float* __restrict__ gK, const int* __restrict__ meta,
                                                const float* __restrict__ scal, double* __restrict__ acc,
                                                unsigned* __restrict__ tick, float* __restrict__ out) {
  const int c = blockIdx.x >> 1, d = blockIdx.x & 1;
  const int n = meta[c];
  const int m0 = meta[32 + c];
  const int m = d ? (n - m0) : m0;
  const int c0 = d ? m0 : 0;
  const int bo = meta[96 + c];
  const float gamma = scal[1 + d];
  const int tid = threadIdx.x;
  const int wv = tid >> 6, lane = tid & 63;

  __shared__ unsigned short Wl[MAXW * WPAD];   // 51072 B
  __shared__ float pS[4 * MAXM];
  __shared__ float pD[4 * MAXM];
  __shared__ float Av[MAXW];
  __shared__ float Sv[MAXW];
  __shared__ float Uv[MAXW];
  __shared__ float Bq[MAXW];
  __shared__ float bc[MAXM];
  __shared__ float th[MAXM + 1];
  __shared__ float gv[MAXM];
  __shared__ float dgv[MAXM];
  __shared__ float pv[MAXM + 1];
  __shared__ float rv[MAXM + 1];
  __shared__ float zv[MAXM + 1];
  __shared__ float xv[MAXM + 1];
  __shared__ double red[16];

  const float* K = gK + bo;
  const int st = n;
  const int mp2 = (m + 1) & ~1;
  const int iw0 = (n * wv) >> 2, iw1 = (n * (wv + 1)) >> 2;

  for (int i = tid >> 2; i < n; i += 64) {
    const float* Kr = K + (size_t)i * st + c0;
    unsigned short* Wr = Wl + i * WPAD;
    for (int j = (tid & 3); j < m; j += 4) {
      unsigned u = __float_as_uint(Kr[j]);
      u += 0x7fffu + ((u >> 16) & 1u);   // RNE to bf16
      Wr[j] = (unsigned short)(u >> 16);
    }
    if ((tid & 3) == 0 && (m & 1)) Wr[m] = 0;
  }
  {
    const int r0 = (m * wv) >> 2, r1 = (m * (wv + 1)) >> 2;
    for (int j = lane; j < m; j += 64) {
      const float* Kr = K + (size_t)(c0 + j) * st + c0;
      float s = 0.f;
      for (int r = r0; r < r1; r++) s += Kr[r];
      pS[wv * MAXM + j] = s;
    }
  }
  __syncthreads();
  for (int j = tid; j < mp2; j += 256) {
    if (j < m) bc[j] = (pS[j] + pS[MAXM + j] + pS[2 * MAXM + j] + pS[3 * MAXM + j]) * (1.0f / 4096.0f);
    th[j] = 0.f;
  }
  __syncthreads();

  for (int it = 0; it < 25; it++) {
    double o = 0.0;
    if (it == 0) {
      const float s0c = gamma * expf(-1.f);
      for (int i = tid; i < n; i += 256) { Av[i] = 0.f; Sv[i] = s0c; o += (double)s0c; }
    } else {
      // merged: Av matvec -> S -> obj contribution (no barrier inside)
      for (int i = tid; i < n; i += 256) {
        const unsigned short* Wr = Wl + i * WPAD;
        float a = 0.f;
#pragma unroll 4
        for (int j = 0; j < mp2; j += 2) {
          unsigned u = *(const unsigned*)(Wr + j);
          a += __uint_as_float(u << 16) * th[j]
             + __uint_as_float(u & 0xffff0000u) * th[j + 1];
        }
        Av[i] = a;
        float si = gamma * expf(fminf(a - 1.f, 30.f));
        Sv[i] = si; o += (double)si;
      }
      for (int j = tid; j < m; j += 256) {
        float t_ = th[j];
        o += (double)(-bc[j] * t_ + LAMBDA * t_ * t_);
      }
    }
    __syncthreads();
    // ---- gradient (+ Jacobi diag at it==0 only; frozen after) ----
    if (it == 0) {
      for (int j = lane; j < m; j += 64) {
        const unsigned short* Wc = Wl + j;
        float s_ = 0.f, ds_ = 0.f;
        int i = iw0;
        for (; i + 3 < iw1; i += 4) {
          float w0 = bf2f(Wc[(i + 0) * WPAD]), w1 = bf2f(Wc[(i + 1) * WPAD]);
          float w2 = bf2f(Wc[(i + 2) * WPAD]), w3 = bf2f(Wc[(i + 3) * WPAD]);
          float a0 = w0 * Sv[i], a1 = w1 * Sv[i + 1], a2 = w2 * Sv[i + 2], a3 = w3 * Sv[i + 3];
          s_ += a0 + a1 + a2 + a3;
          ds_ += a0 * w0 + a1 * w1 + a2 * w2 + a3 * w3;
        }
        for (; i < iw1; i++) { float w = bf2f(Wc[i * WPAD]); float a = w * Sv[i]; s_ += a; ds_ += a * w; }
        pS[wv * MAXM + j] = s_; pD[wv * MAXM + j] = ds_;
      }
    } else {
      for (int j = lane; j < m; j += 64) {
        const unsigned short* Wc = Wl + j;
        float s_ = 0.f;
        int i = iw0;
        for (; i + 3 < iw1; i += 4)
          s_ += bf2f(Wc[(i+0)*WPAD]) * Sv[i]   + bf2f(Wc[(i+1)*WPAD]) * Sv[i+1]
              + bf2f(Wc[(i+2)*WPAD]) * Sv[i+2] + bf2f(Wc[(i+3)*WPAD]) * Sv[i+3];
        for (; i < iw1; i++) s_ += bf2f(Wc[i * WPAD]) * Sv[i];
        pS[wv * MAXM + j] = s_;
      }
    }
    __syncthreads();
    double gm = 0.0;
    for (int j = tid; j < m; j += 256) {
      float s_ = pS[j] + pS[MAXM + j] + pS[2 * MAXM + j] + pS[3 * MAXM + j];
      if (it == 0) {
        float ds_ = pD[j] + pD[MAXM + j] + pD[2 * MAXM + j] + pD[3 * MAXM + j];
        dgv[j] = ds_ + 2.f * LAMBDA;
      }
      float g = s_ - bc[j] + 2.f * LAMBDA * th[j];
      gv[j] = g;
      double ag = fabs((double)g); if (ag > gm) gm = ag;
    }
    double obj, gmax;
    blockReduceSumMax(o, gm, red, obj, gmax);
    if (gmax < 1e-5) break;

    // ---- PCG solve H x = -g (frozen Jacobi precond), inexact-Newton tol ----
    const double tolf = (it == 0) ? 1e-2 : ((it == 1) ? 1e-3 : 1e-4);
    double rz = 0.0;
    for (int j = tid; j < mp2; j += 256) {
      float r0 = (j < m) ? -gv[j] : 0.f;
      float z0 = (j < m) ? r0 / dgv[j] : 0.f;
      rv[j] = r0; zv[j] = z0; pv[j] = z0; xv[j] = 0.f;
      rz += (double)r0 * (double)z0;
    }
    rz = blockReduceSum(rz, red);
    double rz0 = rz;
    double gtpacc = 0.0;   // block-uniform: sum of alpha_k * rz_k = -g^T x
    for (int cg = 0; cg < 12; cg++) {
      __syncthreads();
      for (int i = tid; i < n; i += 256) {
        const unsigned short* Wr = Wl + i * WPAD;
        float a = 0.f;
#pragma unroll 4
        for (int j = 0; j < mp2; j += 2) {
          unsigned u = *(const unsigned*)(Wr + j);
          a += __uint_as_float(u << 16) * pv[j]
             + __uint_as_float(u & 0xffff0000u) * pv[j + 1];
        }
        Uv[i] = a * Sv[i];
      }
      __syncthreads();
      for (int j = lane; j < m; j += 64) {
        const unsigned short* Wc = Wl + j;
        float q = 0.f;
        int i = iw0;
        for (; i + 3 < iw1; i += 4)
          q += bf2f(Wc[(i+0)*WPAD]) * Uv[i]   + bf2f(Wc[(i+1)*WPAD]) * Uv[i+1]
             + bf2f(Wc[(i+2)*WPAD]) * Uv[i+2] + bf2f(Wc[(i+3)*WPAD]) * Uv[i+3];
        for (; i < iw1; i++) q += bf2f(Wc[i * WPAD]) * Uv[i];
        pS[wv * MAXM + j] = q;
      }
      __syncthreads();
      double pq = 0.0;
      for (int j = tid; j < m; j += 256) {
        float q = pS[j] + pS[MAXM + j] + pS[2 * MAXM + j] + pS[3 * MAXM + j] + 2.f * LAMBDA * pv[j];
        Bq[j] = q;
        pq += (double)pv[j] * (double)q;
      }
      pq = blockReduceSum(pq, red);
      if (!(pq > 0.0)) break;
      float alpha = (float)(rz / pq);
      gtpacc += (double)alpha * rz;
      double rznew = 0.0;
      for (int j = tid; j < m; j += 256) {
        xv[j] += alpha * pv[j];
        float rn = rv[j] - alpha * Bq[j];
        rv[j] = rn;
        float zn = rn / dgv[j];
        zv[j] = zn;
        rznew += (double)rn * (double)zn;
      }
      rznew = blockReduceSum(rznew, red);
      if (rznew < tolf * rz0 || cg == 11) break;
      float beta = (float)(rznew / rz);
      for (int j = tid; j < m; j += 256) pv[j] = zv[j] + beta * pv[j];
      rz = rznew;
    }
    __syncthreads();
    // gtp = g^T x = -gtpacc (exact CG identity); no reduction phase needed
    double gtp = -gtpacc;
    if (!(gtp < 0.0)) break;   // no CG progress => converged/degenerate

    float t = 1.f;
    if (-gtp >= 1e-4) {
      for (int i = tid; i < n; i += 256) {
        const unsigned short* Wr = Wl + i * WPAD;
        float a = 0.f;
#pragma unroll 4
        for (int j = 0; j < mp2; j += 2) {
          unsigned u = *(const unsigned*)(Wr + j);
          a += __uint_as_float(u << 16) * xv[j]
             + __uint_as_float(u & 0xffff0000u) * xv[j + 1];
        }
        Bq[i] = a;
      }
      __syncthreads();
      for (int ls = 0; ls < 10; ls++) {
        double ol = 0.0;
        for (int i = tid; i < n; i += 256)
          ol += (double)(gamma * expf(fminf(Av[i] + t * Bq[i] - 1.f, 30.f)));
        for (int j = tid; j < m; j += 256) {
          float tj = th[j] + t * xv[j];
          ol += (double)(-bc[j] * tj + LAMBDA * tj * tj);
        }
        double ot2 = blockReduceSum(ol, red);
        if (ot2 <= obj + 1e-4 * (double)t * gtp) break;
        t *= 0.5f;
      }
    }
    for (int j = tid; j < mp2; j += 256) th[j] += t * xv[j];
    __syncthreads();
  }

  // ---- final exact f32 evaluation (global K, f32 theta) ----
  __syncthreads();
  for (int i = tid; i < n; i += 256) {
    const float* Kr = K + (size_t)i * st + c0;
    float a = 0.f;
    int j = 0;
    for (; j + 7 < m; j += 8)
      a += th[j] * Kr[j] + th[j+1] * Kr[j+1] + th[j+2] * Kr[j+2] + th[j+3] * Kr[j+3]
         + th[j+4] * Kr[j+4] + th[j+5] * Kr[j+5] + th[j+6] * Kr[j+6] + th[j+7] * Kr[j+7];
    for (; j < m; j++) a += th[j] * Kr[j];
    Av[i] = a;
  }
  __syncthreads();
  double t1l = 0.0, t2l = 0.0;
  for (int i = tid; i < n; i += 256) t2l += (double)(gamma * expf(fminf(Av[i] - 1.f, 30.f)));
  for (int j = tid; j < m; j += 256) t1l += (double)(bc[j] * th[j]);
  double t1 = blockReduceSum(t1l, red);
  double t2 = blockReduceSum(t2l, red);
  if (tid == 0) {
    atomicAdd(&acc[0], t1);
    atomicAdd(&acc[1], t2);
    __threadfence();
    unsigned old = __hip_atomic_fetch_add(&tick[0], 1u, __ATOMIC_ACQ_REL, __HIP_MEMORY_SCOPE_AGENT);
    if (old == 61u) {
      double a0 = __hip_atomic_load(&acc[0], __ATOMIC_RELAXED, __HIP_MEMORY_SCOPE_AGENT);
      double a1 = __hip_atomic_load(&acc[1], __ATOMIC_RELAXED, __HIP_MEMORY_SCOPE_AGENT);
      out[0] = (float)(a0 - a1);
    }
  }
}

// ---------------- launcher ----------------
extern "C" void kernel_launch(void* const* d_in, const int* in_sizes, int n_in,
                              void* d_out, int out_size, void* d_ws, size_t ws_size,
                              hipStream_t stream) {
  const float* sf = (const float*)d_in[0];
  const float* tf = (const float*)d_in[1];
  const int* y = (const int*)d_in[2];
  const int* l = (const int*)d_in[3];
  char* ws = (char*)d_ws;

  double*   acc    = (double*)(ws + WS_ACC);
  unsigned* hist0  = (unsigned*)(ws + WS_HIST0);
  unsigned* histA  = (unsigned*)(ws + WS_HISTA);
  unsigned* histB  = (unsigned*)(ws + WS_HISTB);
  unsigned* h2A    = (unsigned*)(ws + WS_H2A);
  unsigned* h2B    = (unsigned*)(ws + WS_H2B);
  unsigned* state  = (unsigned*)(ws + WS_STATE);
  unsigned* tick   = (unsigned*)(ws + WS_TICK);
  int*      meta   = (int*)(ws + WS_META);
  float*    scal   = (float*)(ws + WS_SCAL);
  int*      perm   = (int*)(ws + WS_PERM);
  float*    xnp    = (float*)(ws + WS_XN);
  float*    Ds     = (float*)(ws + WS_DS);
  float*    gK     = (float*)(ws + WS_KBLK);

  hipMemsetAsync(d_ws, 0, ZERO_BYTES, stream);
  hipLaunchKernelGGL(xn_kernel, dim3(1024), dim3(256), 0, stream, sf, tf, xnp);
  hipLaunchKernelGGL(dist_k, dim3(528), dim3(16, 16), 0, stream, sf, xnp, Ds, hist0);
  hipLaunchKernelGGL(scan0_k, dim3(1), dim3(256), 0, stream, hist0, state);
  hipLaunchKernelGGL(hist1_k, dim3(512), dim3(256), 0, stream, Ds, state, histA, histB);
  hipLaunchKernelGGL(scan1_k, dim3(1), dim3(256), 0, stream, histA, histB, state);
  hipLaunchKernelGGL(hist2_k, dim3(512), dim3(256), 0, stream, Ds, state, h2A, h2B);
  hipLaunchKernelGGL(scan2b_k, dim3(1), dim3(256), 0, stream, h2A, h2B, state, scal, y, l, perm, meta);
  hipLaunchKernelGGL(build_k, dim3(105, 1, NCLASS), dim3(16, 16), 0, stream, sf, tf, xnp, perm, meta, scal, gK);
  hipLaunchKernelGGL(solver_k, dim3(62), dim3(256), 0, stream, gK, meta, scal, acc, tick, (float*)d_out);
}